// Round 4
// baseline (253.325 us; speedup 1.0000x reference)
//
#include <hip/hip_runtime.h>
#include <hip/hip_bf16.h>
#include <math.h>

// Problem constants
#define Bn  2
#define Nn  512
#define Dn  128
#define FHn 512

#define PI_F 3.14159265358979323846f

typedef __hip_bfloat16 bf16;

__device__ __forceinline__ float cvt(float x) { return x; }
__device__ __forceinline__ float cvt(bf16 x) { return __bfloat162float(x); }
__device__ __forceinline__ float sigmoidf_(float x) { return 1.0f / (1.0f + __expf(-x)); }
__device__ __forceinline__ bool is_bf16(const void* alpha) {
    return ((const unsigned short*)alpha)[0] == 0x3F80;
}

// fast atan2, max abs err ~2e-5 rad (output guaranteed in [-pi, pi])
__device__ __forceinline__ float fatan2f(float dy, float dx) {
    float ax = fabsf(dx), ay = fabsf(dy);
    float mx = fmaxf(ax, ay), mn = fminf(ax, ay);
    float r = __fdividef(mn, mx);
    float t = r * r;
    float a = r * (0.99997726f + t * (-0.33262347f + t * (0.19354346f +
              t * (-0.11643287f + t * (0.05265332f + t * (-0.01172120f))))));
    if (ay > ax) a = 1.57079632679489662f - a;
    if (dx < 0.f) a = PI_F - a;
    if (dy < 0.f) a = -a;
    return fminf(fmaxf(a, -PI_F), PI_F);
}

// ---------------------------------------------------------------------------
// Workspace layout (float offsets). S = one (B,N,D) f32 slab.
#define S_ 131072
#define WS_Q    (0 * S_)
#define WS_K    (1 * S_)
#define WS_V    (2 * S_)
#define WS_MH   (3 * S_)
#define WS_T    (4 * S_)
#define WS_OP   (5 * S_)
#define WS_ST   (6 * S_)

// stats region (float offsets inside WS_ST)
#define ST_IN_SC   0      // 512: [which*256 + b*128 + d]
#define ST_IN_SH   512
#define ST_X_SC    2048
#define ST_X_SH    2304
#define ST_PRE     3072
#define P_SC       1024   // cds, cdt, cas, cat, gate_b, outlin_b, alpha (7)
#define ST_TAB     4224   // 1288 floats of piecewise-linear tables
#define TAB_ANG 644
#define TAB_N   1288
// bucket->segment LUTs (257 each), contiguous right after the tables
#define ST_LUTC (ST_TAB + TAB_N)        // 5512
#define ST_LUTA (ST_LUTC + 257)         // 5769
#define TABLUT_N (TAB_N + 514)          // 1802 contiguous floats

#define SMEM_FLOATS 2568   // 2560 work + 8 reduce scratch (256-thread kernels)

struct KP {
    const void *row, *col, *cost, *coords, *alpha;
    const void *n1w, *n1b, *n2w, *n2b, *n3w, *n3b, *f1w, *f1b, *f2w, *f2b;
    const void *qw, *qb, *kw, *kb, *vw, *vb, *pw, *pb, *mw, *mb;
    const void *dw1, *db1, *dw2, *db2, *aw1, *ab1, *aw2, *ab2, *gw, *gb, *ow, *ob;
    const void *ffw1, *ffb1, *ffw2, *ffb2;
    void* out;
    float* ws;
};

// ---------------------------------------------------------------------------
// Block-level reductions (256 threads). scr >= 8 floats. All threads get result.
__device__ __forceinline__ void blk_sum2(float& s, float& ss, volatile float* scr) {
#pragma unroll
    for (int off = 32; off > 0; off >>= 1) { s += __shfl_down(s, off); ss += __shfl_down(ss, off); }
    __syncthreads();
    int wave = threadIdx.x >> 6, lane = threadIdx.x & 63;
    if (lane == 0) { scr[wave] = s; scr[4 + wave] = ss; }
    __syncthreads();
    s = scr[0] + scr[1] + scr[2] + scr[3];
    ss = scr[4] + scr[5] + scr[6] + scr[7];
}

// ---------------------------------------------------------------------------
// Build piecewise-linear tables for one scalar MLP — fully parallel.
// Also leaves the SORTED breakpoints in smem+768 (128 floats) for LUT build.
template <typename T>
__device__ void build_tables(const T* w1p, const T* b1p, const T* w2p,
                             const T* owp, const T* gwp, float* gtab, float* smem) {
    int tid = threadIdx.x;
    float* W  = smem;          // 128
    float* Bb = smem + 128;
    float* U  = smem + 256;
    float* Vv = smem + 384;
    float* Tt = smem + 512;
    int* RK   = (int*)(smem + 640);   // 128 ranks
    float* STl = smem + 768;          // sorted breakpoints (LDS copy)
    if (tid < 128) {
        float u = 0.f, v = 0.f;
#pragma unroll 4
        for (int d = 0; d < Dn; ++d) {
            float w2 = cvt(w2p[tid * Dn + d]);
            u += w2 * cvt(owp[d]);
            v += w2 * cvt(gwp[d]);
        }
        float w = cvt(w1p[tid]), b = cvt(b1p[tid]);
        U[tid] = u; Vv[tid] = v; W[tid] = w; Bb[tid] = b;
        Tt[tid] = (w != 0.f) ? (-b / w) : 3.0e38f;
    }
    __syncthreads();
    if (tid < 128) {
        float tk = Tt[tid]; int r = 0;
        for (int j = 0; j < 128; ++j) {
            float tj = Tt[j];
            r += (tj < tk) || (tj == tk && j < tid);
        }
        RK[tid] = r;
        gtab[r] = tk;        // sorted breakpoint table (scatter by rank)
        STl[r] = tk;         // LDS copy for LUT build
    }
    __syncthreads();
    if (tid <= 128) {
        int si = tid;
        float slS = 0, inS = 0, slT = 0, inT = 0;
        for (int k = 0; k < 128; ++k) {
            float w = W[k];
            if (w == 0.f) {
                float rb = fmaxf(Bb[k], 0.f);
                inS += rb * U[k];
                inT += rb * Vv[k];
            } else {
                bool act = (w > 0.f) ? (RK[k] < si) : (RK[k] >= si);
                if (act) {
                    slS += w * U[k];  inS += Bb[k] * U[k];
                    slT += w * Vv[k]; inT += Bb[k] * Vv[k];
                }
            }
        }
        gtab[128 + si] = slS;
        gtab[257 + si] = inS;
        gtab[386 + si] = slT;
        gtab[515 + si] = inT;
    }
}

// count of sorted breakpoints <= c over LDS array of 128
__device__ __forceinline__ int bsearch128(const float* T, float c) {
    int lo = 0, hi = 128;
    while (lo < hi) { int mid = (lo + hi) >> 1; if (T[mid] <= c) lo = mid + 1; else hi = mid; }
    return lo;
}

// ---------------------------------------------------------------------------
// Phase 0: input instance-norm stats (512 cols, 1/block); block 128 = scalar
// constants; blocks 129/130 = dist/angle piecewise tables + bucket LUTs.
template <typename T>
__device__ void phase0(const KP& p, float* st, float* smem) {
    float* scr = smem + 2560;
    int cid = blockIdx.x;    // 0..511
    int tid = threadIdx.x;
    {
        int which = cid >> 8, b = (cid >> 7) & 1, d = cid & 127;
        const T* src = (const T*)(which ? p.col : p.row) + (size_t)b * Nn * Dn + d;
        float x0 = cvt(src[(size_t)tid * Dn]);
        float x1 = cvt(src[(size_t)(tid + 256) * Dn]);
        float s = x0 + x1, ss = x0 * x0 + x1 * x1;
        blk_sum2(s, ss, scr);
        if (tid == 0) {
            float m = s * (1.f / Nn);
            float v = fmaxf(ss * (1.f / Nn) - m * m, 0.f);
            float rstd = rsqrtf(v + 1e-5f);
            const T* w = which ? (const T*)p.n2w : (const T*)p.n1w;
            const T* bb = which ? (const T*)p.n2b : (const T*)p.n1b;
            float sc = rstd * cvt(w[d]);
            st[ST_IN_SC + cid] = sc;
            st[ST_IN_SH + cid] = cvt(bb[d]) - m * sc;
        }
    }
    __syncthreads();
    if (cid == 128) {
        const T* db2 = (const T*)p.db2; const T* ab2 = (const T*)p.ab2;
        const T* ow = (const T*)p.ow;   const T* gw = (const T*)p.gw;
        float d2 = 0.f, a2 = 0.f, o = 0.f, g0 = 0.f, g1 = 0.f;
        if (tid < 128) {
            d2 = cvt(db2[tid]); a2 = cvt(ab2[tid]);
            o = cvt(ow[tid]); g0 = cvt(gw[tid]); g1 = cvt(gw[Dn + tid]);
        }
        float cds = d2 * o, cdt = d2 * g0, cas = a2 * o, cat = a2 * g1;
        blk_sum2(cds, cdt, scr);
        blk_sum2(cas, cat, scr);
        if (tid == 0) {
            float* pre = st + ST_PRE;
            pre[P_SC + 0] = cds; pre[P_SC + 1] = cdt;
            pre[P_SC + 2] = cas; pre[P_SC + 3] = cat;
            pre[P_SC + 4] = cvt(((const T*)p.gb)[0]);
            pre[P_SC + 5] = cvt(((const T*)p.ob)[0]);
            pre[P_SC + 6] = cvt(((const T*)p.alpha)[0]);
        }
    } else if (cid == 129) {
        build_tables<T>((const T*)p.dw1, (const T*)p.db1, (const T*)p.dw2,
                        (const T*)p.ow, (const T*)p.gw, st + ST_TAB, smem);
        __syncthreads();
        const float* STl = smem + 768;
        for (int e = tid; e < 257; e += 256) {
            float c = e * (1.f / 256.f);                 // cost domain [0,1]
            st[ST_LUTC + e] = (float)bsearch128(STl, c);
        }
    } else if (cid == 130) {
        build_tables<T>((const T*)p.aw1, (const T*)p.ab1, (const T*)p.aw2,
                        (const T*)p.ow, (const T*)p.gw + Dn, st + ST_TAB + TAB_ANG, smem);
        __syncthreads();
        const float* STl = smem + 768;
        for (int e = tid; e < 257; e += 256) {
            float a = -PI_F + e * (PI_F / 128.f);        // angle domain [-pi,pi]
            st[ST_LUTA + e] = (float)bsearch128(STl, a);
        }
    }
}

// ---------------------------------------------------------------------------
// Phase 1: QKV only. 4 rows/block, 512 threads, 256 blocks (R2-verified).
template <typename T>
__device__ void phase1(const KP& p, float* st, float* smem) {
    int tid = threadIdx.x;
    int r0 = blockIdx.x * 4;     // rows r0..r0+3 (0..1023)
    int b = r0 >> 9;
    const T* row = (const T*)p.row; const T* col = (const T*)p.col;
    float* ws = p.ws;
    float* Q = ws + WS_Q; float* Kraw = ws + WS_K; float* V = ws + WS_V;

    float* lr = smem;            // [4][128]
    float* lc = smem + 512;      // [4][128]
    float* redq = smem + 1024;   // [4(q)][4(r)][128]
    float* redk = smem + 3072;
    float* redv = smem + 5120;
    {
        int r = tid >> 7, d = tid & 127;
        float scR = st[ST_IN_SC + b * 128 + d],       shR = st[ST_IN_SH + b * 128 + d];
        float scC = st[ST_IN_SC + 256 + b * 128 + d], shC = st[ST_IN_SH + 256 + b * 128 + d];
        lr[r * 128 + d] = cvt(row[(size_t)(r0 + r) * Dn + d]) * scR + shR;
        lc[r * 128 + d] = cvt(col[(size_t)(r0 + r) * Dn + d]) * scC + shC;
    }
    __syncthreads();
    {
        int h = tid & 127, q = tid >> 7;
        const T* qw = (const T*)p.qw; const T* kw = (const T*)p.kw; const T* vw = (const T*)p.vw;
        float aq[4] = {0,0,0,0}, ak[4] = {0,0,0,0}, av[4] = {0,0,0,0};
        int ks = q * 32;
#pragma unroll 8
        for (int k = ks; k < ks + 32; ++k) {
            float wq = cvt(qw[k * Dn + h]);
            float wk = cvt(kw[k * Dn + h]);
            float wv = cvt(vw[k * Dn + h]);
#pragma unroll
            for (int r = 0; r < 4; ++r) {
                aq[r] += lr[r * 128 + k] * wq;
                ak[r] += lc[r * 128 + k] * wk;
                av[r] += lc[r * 128 + k] * wv;
            }
        }
#pragma unroll
        for (int r = 0; r < 4; ++r) {
            redq[q * 512 + r * 128 + h] = aq[r];
            redk[q * 512 + r * 128 + h] = ak[r];
            redv[q * 512 + r * 128 + h] = av[r];
        }
    }
    __syncthreads();
    if (tid < 128) {
        int h = tid;
        float bq = cvt(((const T*)p.qb)[h]);
        float bk = cvt(((const T*)p.kb)[h]);
        float bv = cvt(((const T*)p.vb)[h]);
#pragma unroll
        for (int r = 0; r < 4; ++r) {
            float qv = redq[r*128+h] + redq[512 + r*128+h] + redq[1024 + r*128+h] + redq[1536 + r*128+h] + bq;
            float kv = redk[r*128+h] + redk[512 + r*128+h] + redk[1024 + r*128+h] + redk[1536 + r*128+h] + bk;
            float vv = redv[r*128+h] + redv[512 + r*128+h] + redv[1024 + r*128+h] + redv[1536 + r*128+h] + bv;
            Q[(r0 + r) * Dn + h]    = sigmoidf_(qv);
            Kraw[(r0 + r) * Dn + h] = kv;
            V[(r0 + r) * Dn + h]    = vv;
        }
    }
}

// ---------------------------------------------------------------------------
// Phase 3 (fused): eab inline (4 rows, LDS-only) + K-softmax recompute +
// num/den with on-the-fly eK/eKV + p/mhc projections. 256 blocks x 512 thr.
// LDS: ab[2048] | redn[2048] | redd[2048] | gl[512] | yl[512] | scr[64]
//      tab+luts [1802] overlaid on redn/redd during eab step.
template <typename T>
__device__ void phase3(const KP& p, float* st, float* smem) {
    int tid = threadIdx.x;
    int r0 = blockIdx.x * 4;
    int b = r0 >> 9;
    float* ws = p.ws;
    const float* Kraw = ws + WS_K;
    const float* V = ws + WS_V;
    const float* Q = ws + WS_Q;
    float* mh = ws + WS_MH;

    float* ab   = smem;          // 2048
    float* redn = smem + 2048;   // 2048
    float* redd = smem + 4096;   // 2048
    float* gl   = smem + 6144;   // 512
    float* yl   = smem + 6656;   // 512
    float* scr  = smem + 7168;   // 64

    // ---- step 1: eab for rows r0..r0+3, one j per thread, into ab[] ----
    {
        float* tab  = smem + 2048;   // [1288] overlays redn
        float* lutc = smem + 3336;   // [257]
        float* luta = smem + 3593;   // [257]  (ends 3850 < 4096+...)
        const float* gt = st + ST_TAB;
        for (int e = tid; e < TABLUT_N; e += 512) tab[e] = gt[e];
        __syncthreads();
        const float* pre = st + ST_PRE;
        float cds = pre[P_SC + 0], cdt = pre[P_SC + 1], cas = pre[P_SC + 2], cat = pre[P_SC + 3];
        float gbias = pre[P_SC + 4], obias = pre[P_SC + 5], alpha = pre[P_SC + 6];
        const T* cost = (const T*)p.cost;
        const T* coords = (const T*)p.coords;
        const float* tabA = tab + TAB_ANG;

        int j = tid;
        float cjx = cvt(coords[((size_t)b * Nn + j) * 2 + 0]);
        float cjy = cvt(coords[((size_t)b * Nn + j) * 2 + 1]);
        float av[4];
#pragma unroll
        for (int rr = 0; rr < 4; ++rr) {
            int i = (r0 + rr) & 511;
            float cix = cvt(coords[((size_t)b * Nn + i) * 2 + 0]);
            float ciy = cvt(coords[((size_t)b * Nn + i) * 2 + 1]);
            float c = cvt(cost[(size_t)b * Nn * Nn + (size_t)i * Nn + j]);
            int k = (int)(c * 256.f); k = k < 0 ? 0 : (k > 255 ? 255 : k);
            int lo = (int)lutc[k], hi = (int)lutc[k + 1];
            while (lo < hi && tab[lo] <= c) ++lo;
            float sd = fmaf(tab[128 + lo], c, tab[257 + lo]) + cds;
            float td = fmaf(tab[386 + lo], c, tab[515 + lo]) + cdt;
            float dx = cix - cjx;
            float dy = ciy - cjy;
            float ang = (dx == 0.f && dy == 0.f) ? 0.f : fatan2f(dy, dx);
            int ka = (int)((ang + PI_F) * (128.f / PI_F)); ka = ka < 0 ? 0 : (ka > 255 ? 255 : ka);
            int la = (int)luta[ka], ha = (int)luta[ka + 1];
            while (la < ha && tabA[la] <= ang) ++la;
            float sa = fmaf(tabA[128 + la], ang, tabA[257 + la]) + cas;
            float ta = fmaf(tabA[386 + la], ang, tabA[515 + la]) + cat;
            float gv = sigmoidf_(td + ta + gbias);
            av[rr] = alpha * (gv * sd + (1.f - gv) * sa + obias);
        }
        // per-row softmax over 512 (register + scr), then store exp(e*rs) to ab
        int wave = tid >> 6, lane = tid & 63;
        float t0 = av[0], t1 = av[1], t2 = av[2], t3 = av[3];
#pragma unroll
        for (int off = 32; off > 0; off >>= 1) {
            t0 = fmaxf(t0, __shfl_down(t0, off));
            t1 = fmaxf(t1, __shfl_down(t1, off));
            t2 = fmaxf(t2, __shfl_down(t2, off));
            t3 = fmaxf(t3, __shfl_down(t3, off));
        }
        __syncthreads();   // also fences tab reads before later overwrite
        if (lane == 0) { scr[wave] = t0; scr[8 + wave] = t1; scr[16 + wave] = t2; scr[24 + wave] = t3; }
        __syncthreads();
        float mx[4], ev[4];
#pragma unroll
        for (int rr = 0; rr < 4; ++rr) {
            float m = scr[rr * 8];
#pragma unroll
            for (int w = 1; w < 8; ++w) m = fmaxf(m, scr[rr * 8 + w]);
            mx[rr] = m;
            ev[rr] = __expf(av[rr] - m);
        }
        float s0 = ev[0], s1 = ev[1], s2 = ev[2], s3 = ev[3];
#pragma unroll
        for (int off = 32; off > 0; off >>= 1) {
            s0 += __shfl_down(s0, off);
            s1 += __shfl_down(s1, off);
            s2 += __shfl_down(s2, off);
            s3 += __shfl_down(s3, off);
        }
        if (lane == 0) { scr[32 + wave] = s0; scr[40 + wave] = s1; scr[48 + wave] = s2; scr[56 + wave] = s3; }
        __syncthreads();
#pragma unroll
        for (int rr = 0; rr < 4; ++rr) {
            float s = 0.f;
#pragma unroll
            for (int w = 0; w < 8; ++w) s += scr[32 + rr * 8 + w];
            ab[rr * 512 + j] = __expf(ev[rr] / s);
        }
    }
    __syncthreads();   // ab complete; tab region free for redn/redd reuse

    int h = tid & 127, q = tid >> 7;   // q in 0..3
    const float* kbase = Kraw + (size_t)b * Nn * Dn + h;
    const float* vbase = V + (size_t)b * Nn * Dn + h;
    int j0 = q * 128;

    // ---- step 2: K-softmax stats over tokens for this thread's h ----
    float mxk, rsk;
    {
        float lm = -3.0e38f;
        for (int j = j0; j < j0 + 128; ++j) lm = fmaxf(lm, kbase[(size_t)j * Dn]);
        redn[q * 128 + h] = lm;
        __syncthreads();
        mxk = fmaxf(fmaxf(redn[h], redn[128 + h]), fmaxf(redn[256 + h], redn[384 + h]));
        float ls = 0.f;
        for (int j = j0; j < j0 + 128; ++j) ls += __expf(kbase[(size_t)j * Dn] - mxk);
        redd[q * 128 + h] = ls;
        __syncthreads();
        rsk = 1.f / (redd[h] + redd[128 + h] + redd[256 + h] + redd[384 + h]);
    }
    __syncthreads();   // stats consumed; redn/redd free

    // ---- step 3: num/den with on-the-fly eK/eKV ----
    {
        float num[4] = {0,0,0,0}, den[4] = {0,0,0,0};
#pragma unroll 4
        for (int j = j0; j < j0 + 128; ++j) {
            float kv_ = kbase[(size_t)j * Dn];
            float ek = __expf(__expf(kv_ - mxk) * rsk);
            float ev_ = ek * vbase[(size_t)j * Dn];
#pragma unroll
            for (int r = 0; r < 4; ++r) {
                num[r] += ab[r * 512 + j] * ev_;
                den[r] += ab[r * 512 + j] * ek;
            }
        }
#pragma unroll
        for (int r = 0; r < 4; ++r) {
            redn[q * 512 + r * 128 + h] = num[r];
            redd[q * 512 + r * 128 + h] = den[r];
        }
    }
    __syncthreads();
    if (tid < 128) {
#pragma unroll
        for (int r = 0; r < 4; ++r) {
            float nu = redn[r * 128 + h] + redn[512 + r * 128 + h]
                     + redn[1024 + r * 128 + h] + redn[1536 + r * 128 + h];
            float de = redd[r * 128 + h] + redd[512 + r * 128 + h]
                     + redd[1024 + r * 128 + h] + redd[1536 + r * 128 + h];
            gl[r * 128 + h] = Q[(r0 + r) * Dn + h] * nu / de;
        }
    }
    __syncthreads();
    {   // Yt = G@pw + pb : k-quarter of 32
        const T* pw = (const T*)p.pw;
        float acc[4] = {0,0,0,0};
        int ks = q * 32;
#pragma unroll 8
        for (int k = ks; k < ks + 32; ++k) {
            float w = cvt(pw[k * Dn + h]);
#pragma unroll
            for (int r = 0; r < 4; ++r) acc[r] += gl[r * 128 + k] * w;
        }
#pragma unroll
        for (int r = 0; r < 4; ++r) redn[q * 512 + r * 128 + h] = acc[r];
    }
    __syncthreads();
    if (tid < 128) {
        float bp = cvt(((const T*)p.pb)[h]);
#pragma unroll
        for (int r = 0; r < 4; ++r)
            yl[r * 128 + h] = redn[r * 128 + h] + redn[512 + r * 128 + h]
                            + redn[1024 + r * 128 + h] + redn[1536 + r * 128 + h] + bp;
    }
    __syncthreads();
    {   // mh = Yt@mw + mb
        const T* mw = (const T*)p.mw;
        float acc[4] = {0,0,0,0};
        int ks = q * 32;
#pragma unroll 8
        for (int k = ks; k < ks + 32; ++k) {
            float w = cvt(mw[k * Dn + h]);
#pragma unroll
            for (int r = 0; r < 4; ++r) acc[r] += yl[r * 128 + k] * w;
        }
#pragma unroll
        for (int r = 0; r < 4; ++r) redn[q * 512 + r * 128 + h] = acc[r];
    }
    __syncthreads();
    if (tid < 128) {
        float bm = cvt(((const T*)p.mb)[h]);
#pragma unroll
        for (int r = 0; r < 4; ++r)
            mh[(r0 + r) * Dn + h] = redn[r * 128 + h] + redn[512 + r * 128 + h]
                                  + redn[1024 + r * 128 + h] + redn[1536 + r * 128 + h] + bm;
    }
}

// ---------------------------------------------------------------------------
// Phase 4+5 fused: per-column mh stats (local) -> t build -> x stats. 256 blocks.
template <typename T>
__device__ void phase45(const KP& p, float* st, float* smem) {
    float* scr = smem + 2560;
    int tid = threadIdx.x;
    int c = blockIdx.x;          // 0..255
    int b = c >> 7, d = c & 127;
    const float* mh = p.ws + WS_MH;
    const float* mp = mh + (size_t)b * Nn * Dn + d;
    float m0 = mp[(size_t)tid * Dn], m1 = mp[(size_t)(tid + 256) * Dn];
    float s = m0 + m1, ss = m0 * m0 + m1 * m1;
    blk_sum2(s, ss, scr);
    float mm = s * (1.f / Nn);
    float vv = fmaxf(ss * (1.f / Nn) - mm * mm, 0.f);
    float rstd = rsqrtf(vv + 1e-5f);
    float scM = rstd * cvt(((const T*)p.n3w)[d]);
    float shM = cvt(((const T*)p.n3b)[d]) - mm * scM;
    const T* row = (const T*)p.row;
    float scI = st[ST_IN_SC + c], shI = st[ST_IN_SH + c];
    const T* rp = row + (size_t)b * Nn * Dn + d;
    float* tp = p.ws + WS_T + (size_t)b * Nn * Dn + d;
    float x0 = cvt(rp[(size_t)tid * Dn]) * scI + shI + m0 * scM + shM;
    float x1 = cvt(rp[(size_t)(tid + 256) * Dn]) * scI + shI + m1 * scM + shM;
    tp[(size_t)tid * Dn] = x0;
    tp[(size_t)(tid + 256) * Dn] = x1;
    __syncthreads();
    float s2 = x0 + x1, ss2 = x0 * x0 + x1 * x1;
    blk_sum2(s2, ss2, scr);
    if (tid == 0) {
        float m = s2 * (1.f / Nn);
        float v = fmaxf(ss2 * (1.f / Nn) - m * m, 0.f);
        float r = rsqrtf(v + 1e-5f);
        float sc = r * cvt(((const T*)p.f1w)[d]);
        st[ST_X_SC + c] = sc;
        st[ST_X_SH + c] = cvt(((const T*)p.f1b)[d]) - m * sc;
    }
}

// ---------------------------------------------------------------------------
// Phase 6: FFN (x normalized inline). 4 rows/block, 512 threads, 256 blocks.
template <typename T>
__device__ void phase6(const KP& p, float* st, float* smem) {
    int tid = threadIdx.x;
    int r0 = blockIdx.x * 4;
    int b = r0 >> 9;
    const float* t = p.ws + WS_T;
    float* outpre = p.ws + WS_OP;
    const T* w1 = (const T*)p.ffw1; const T* b1 = (const T*)p.ffb1;
    const T* w2 = (const T*)p.ffw2; const T* b2 = (const T*)p.ffb2;

    float* xl = smem;            // [4][128] = 512
    float* hl = smem + 512;      // [4][512] = 2048
    float* red = smem + 2560;    // [4(q)][4(r)][128] = 2048
    {
        int r = tid >> 7, d = tid & 127;
        int c = b * 128 + d;
        xl[r * 128 + d] = t[(r0 + r) * Dn + d] * st[ST_X_SC + c] + st[ST_X_SH + c];
    }
    __syncthreads();
    {
        int f = tid;
        float a[4] = {0,0,0,0};
#pragma unroll 4
        for (int k = 0; k < Dn; ++k) {
            float w = cvt(w1[k * FHn + f]);
#pragma unroll
            for (int r = 0; r < 4; ++r) a[r] += xl[r * 128 + k] * w;
        }
        float bb1 = cvt(b1[f]);
#pragma unroll
        for (int r = 0; r < 4; ++r) hl[r * 512 + f] = fmaxf(a[r] + bb1, 0.f);
    }
    __syncthreads();
    {
        int d = tid & 127, q = tid >> 7;
        int k0 = q * 128;
        float a[4] = {0,0,0,0};
#pragma unroll 8
        for (int k = k0; k < k0 + 128; ++k) {
            float w = cvt(w2[k * Dn + d]);
#pragma unroll
            for (int r = 0; r < 4; ++r) a[r] += hl[r * 512 + k] * w;
        }
#pragma unroll
        for (int r = 0; r < 4; ++r) red[q * 512 + r * 128 + d] = a[r];
    }
    __syncthreads();
    if (tid < 128) {
        float bb2 = cvt(b2[tid]);
#pragma unroll
        for (int r = 0; r < 4; ++r) {
            float sum = red[r * 128 + tid] + red[512 + r * 128 + tid]
                      + red[1024 + r * 128 + tid] + red[1536 + r * 128 + tid];
            outpre[(r0 + r) * Dn + tid] = xl[r * 128 + tid] + sum + bb2;
        }
    }
}

// ---------------------------------------------------------------------------
// Phase 7+8 fused: per-column outpre stats (local) -> cast out. 256 blocks.
template <typename T>
__device__ void phase78(const KP& p, float* smem) {
    float* scr = smem + 2560;
    int tid = threadIdx.x;
    int c = blockIdx.x;          // 0..255
    int b = c >> 7, d = c & 127;
    const float* op = p.ws + WS_OP;
    const float* sp = op + (size_t)b * Nn * Dn + d;
    float x0 = sp[(size_t)tid * Dn], x1 = sp[(size_t)(tid + 256) * Dn];
    float s = x0 + x1, ss = x0 * x0 + x1 * x1;
    blk_sum2(s, ss, scr);
    float m = s * (1.f / Nn);
    float v = fmaxf(ss * (1.f / Nn) - m * m, 0.f);
    float rstd = rsqrtf(v + 1e-5f);
    float sc = rstd * cvt(((const T*)p.f2w)[d]);
    float sh = cvt(((const T*)p.f2b)[d]) - m * sc;
    T* out = (T*)p.out + (size_t)b * Nn * Dn + d;
    out[(size_t)tid * Dn] = (T)(x0 * sc + sh);
    out[(size_t)(tid + 256) * Dn] = (T)(x1 * sc + sh);
}

// ---------------------------------------------------------------------------
// Kernel wrappers
#define PH_WRAP(name, call_bf, call_f)                                        \
__global__ __launch_bounds__(256) void name(KP p) {                           \
    __shared__ float smem[SMEM_FLOATS];                                       \
    float* st = p.ws + WS_ST; (void)st;                                       \
    if (is_bf16(p.alpha)) { call_bf; } else { call_f; }                       \
}

PH_WRAP(k_head,  phase0<bf16>(p, st, smem),  phase0<float>(p, st, smem))
__global__ __launch_bounds__(512) void k_qkv(KP p) {
    __shared__ float smem[7168];
    float* st = p.ws + WS_ST;
    if (is_bf16(p.alpha)) phase1<bf16>(p, st, smem);
    else                  phase1<float>(p, st, smem);
}
__global__ __launch_bounds__(512) void k_attn(KP p) {
    __shared__ float smem[7232];   // 28.9 KB
    float* st = p.ws + WS_ST;
    if (is_bf16(p.alpha)) phase3<bf16>(p, st, smem);
    else                  phase3<float>(p, st, smem);
}
PH_WRAP(k_mid,   phase45<bf16>(p, st, smem), phase45<float>(p, st, smem))
__global__ __launch_bounds__(512) void k_ffn(KP p) {
    __shared__ float smem[4608];   // 18 KB
    float* st = p.ws + WS_ST;
    if (is_bf16(p.alpha)) phase6<bf16>(p, st, smem);
    else                  phase6<float>(p, st, smem);
}
PH_WRAP(k_tail,  phase78<bf16>(p, smem),     phase78<float>(p, smem))

// ---------------------------------------------------------------------------
extern "C" void kernel_launch(void* const* d_in, const int* in_sizes, int n_in,
                              void* d_out, int out_size, void* d_ws, size_t ws_size,
                              hipStream_t stream) {
    KP p;
    p.row = d_in[0];  p.col = d_in[1];  p.cost = d_in[2];  p.coords = d_in[3];
    p.alpha = d_in[4];
    p.n1w = d_in[5];  p.n1b = d_in[6];  p.n2w = d_in[7];  p.n2b = d_in[8];
    p.n3w = d_in[9];  p.n3b = d_in[10]; p.f1w = d_in[11]; p.f1b = d_in[12];
    p.f2w = d_in[13]; p.f2b = d_in[14];
    p.qw = d_in[15];  p.qb = d_in[16];  p.kw = d_in[17];  p.kb = d_in[18];
    p.vw = d_in[19];  p.vb = d_in[20];  p.pw = d_in[21];  p.pb = d_in[22];
    p.mw = d_in[23];  p.mb = d_in[24];
    p.dw1 = d_in[25]; p.db1 = d_in[26]; p.dw2 = d_in[27]; p.db2 = d_in[28];
    p.aw1 = d_in[29]; p.ab1 = d_in[30]; p.aw2 = d_in[31]; p.ab2 = d_in[32];
    p.gw = d_in[33];  p.gb = d_in[34];  p.ow = d_in[35];  p.ob = d_in[36];
    p.ffw1 = d_in[37]; p.ffb1 = d_in[38]; p.ffw2 = d_in[39]; p.ffb2 = d_in[40];
    p.out = d_out;
    p.ws = (float*)d_ws;

    k_head<<<512, 256, 0, stream>>>(p);
    k_qkv<<<256, 512, 0, stream>>>(p);
    k_attn<<<256, 512, 0, stream>>>(p);
    k_mid<<<256, 256, 0, stream>>>(p);
    k_ffn<<<256, 512, 0, stream>>>(p);
    k_tail<<<256, 256, 0, stream>>>(p);
}

// Round 5
// 231.498 us; speedup vs baseline: 1.0943x; 1.0943x over previous
//
#include <hip/hip_runtime.h>
#include <hip/hip_bf16.h>
#include <math.h>

// Problem constants
#define Bn  2
#define Nn  512
#define Dn  128
#define FHn 512

#define PI_F 3.14159265358979323846f

typedef __hip_bfloat16 bf16;

__device__ __forceinline__ float cvt(float x) { return x; }
__device__ __forceinline__ float cvt(bf16 x) { return __bfloat162float(x); }
__device__ __forceinline__ float sigmoidf_(float x) { return 1.0f / (1.0f + __expf(-x)); }
__device__ __forceinline__ bool is_bf16(const void* alpha) {
    return ((const unsigned short*)alpha)[0] == 0x3F80;
}

// fast atan2, max abs err ~2e-5 rad (output guaranteed in [-pi, pi])
__device__ __forceinline__ float fatan2f(float dy, float dx) {
    float ax = fabsf(dx), ay = fabsf(dy);
    float mx = fmaxf(ax, ay), mn = fminf(ax, ay);
    float r = __fdividef(mn, mx);
    float t = r * r;
    float a = r * (0.99997726f + t * (-0.33262347f + t * (0.19354346f +
              t * (-0.11643287f + t * (0.05265332f + t * (-0.01172120f))))));
    if (ay > ax) a = 1.57079632679489662f - a;
    if (dx < 0.f) a = PI_F - a;
    if (dy < 0.f) a = -a;
    return fminf(fmaxf(a, -PI_F), PI_F);
}

// ---------------------------------------------------------------------------
// Workspace layout (float offsets). S = one (B,N,D) f32 slab.
#define S_ 131072
#define WS_Q    (0 * S_)
#define WS_K    (1 * S_)
#define WS_V    (2 * S_)
#define WS_EK   (3 * S_)
#define WS_EKV  (4 * S_)
#define WS_MH   (5 * S_)
#define WS_T    (6 * S_)
#define WS_OP   (7 * S_)
#define WS_ST   (8 * S_)

// stats region (float offsets inside WS_ST)
#define ST_IN_SC   0      // 512: [which*256 + b*128 + d]
#define ST_IN_SH   512
#define ST_X_SC    2048
#define ST_X_SH    2304
#define ST_PRE     3072
#define P_SC       1024   // cds, cdt, cas, cat, gate_b, outlin_b, alpha (7)
#define ST_TAB     4224   // 1288 floats of piecewise-linear tables
#define TAB_ANG 644
#define TAB_N   1288
// bucket->segment LUTs (257 each), contiguous right after the tables
#define ST_LUTC (ST_TAB + TAB_N)        // 5512
#define ST_LUTA (ST_LUTC + 257)         // 5769
#define TABLUT_N (TAB_N + 514)          // 1802 contiguous floats

#define SMEM_FLOATS 2568   // 2560 work + 8 reduce scratch (256-thread kernels)

struct KP {
    const void *row, *col, *cost, *coords, *alpha;
    const void *n1w, *n1b, *n2w, *n2b, *n3w, *n3b, *f1w, *f1b, *f2w, *f2b;
    const void *qw, *qb, *kw, *kb, *vw, *vb, *pw, *pb, *mw, *mb;
    const void *dw1, *db1, *dw2, *db2, *aw1, *ab1, *aw2, *ab2, *gw, *gb, *ow, *ob;
    const void *ffw1, *ffb1, *ffw2, *ffb2;
    void* out;
    float* ws;
};

// ---------------------------------------------------------------------------
// Block-level reductions (256 threads). scr >= 8 floats. All threads get result.
__device__ __forceinline__ void blk_sum2(float& s, float& ss, volatile float* scr) {
#pragma unroll
    for (int off = 32; off > 0; off >>= 1) { s += __shfl_down(s, off); ss += __shfl_down(ss, off); }
    __syncthreads();
    int wave = threadIdx.x >> 6, lane = threadIdx.x & 63;
    if (lane == 0) { scr[wave] = s; scr[4 + wave] = ss; }
    __syncthreads();
    s = scr[0] + scr[1] + scr[2] + scr[3];
    ss = scr[4] + scr[5] + scr[6] + scr[7];
}

__device__ __forceinline__ float blk_sum1(float v, volatile float* scr) {
#pragma unroll
    for (int off = 32; off > 0; off >>= 1) v += __shfl_down(v, off);
    __syncthreads();
    int wave = threadIdx.x >> 6, lane = threadIdx.x & 63;
    if (lane == 0) scr[wave] = v;
    __syncthreads();
    return scr[0] + scr[1] + scr[2] + scr[3];
}

__device__ __forceinline__ float blk_max1(float v, volatile float* scr) {
#pragma unroll
    for (int off = 32; off > 0; off >>= 1) v = fmaxf(v, __shfl_down(v, off));
    __syncthreads();
    int wave = threadIdx.x >> 6, lane = threadIdx.x & 63;
    if (lane == 0) scr[wave] = v;
    __syncthreads();
    return fmaxf(fmaxf(scr[0], scr[1]), fmaxf(scr[2], scr[3]));
}

// ---------------------------------------------------------------------------
// Build piecewise-linear tables for one scalar MLP — fully parallel.
// Also leaves the SORTED breakpoints in smem+768 (128 floats) for LUT build.
template <typename T>
__device__ void build_tables(const T* w1p, const T* b1p, const T* w2p,
                             const T* owp, const T* gwp, float* gtab, float* smem) {
    int tid = threadIdx.x;
    float* W  = smem;          // 128
    float* Bb = smem + 128;
    float* U  = smem + 256;
    float* Vv = smem + 384;
    float* Tt = smem + 512;
    int* RK   = (int*)(smem + 640);   // 128 ranks
    float* STl = smem + 768;          // sorted breakpoints (LDS copy)
    if (tid < 128) {
        float u = 0.f, v = 0.f;
#pragma unroll 4
        for (int d = 0; d < Dn; ++d) {
            float w2 = cvt(w2p[tid * Dn + d]);
            u += w2 * cvt(owp[d]);
            v += w2 * cvt(gwp[d]);
        }
        float w = cvt(w1p[tid]), b = cvt(b1p[tid]);
        U[tid] = u; Vv[tid] = v; W[tid] = w; Bb[tid] = b;
        Tt[tid] = (w != 0.f) ? (-b / w) : 3.0e38f;
    }
    __syncthreads();
    if (tid < 128) {
        float tk = Tt[tid]; int r = 0;
        for (int j = 0; j < 128; ++j) {
            float tj = Tt[j];
            r += (tj < tk) || (tj == tk && j < tid);
        }
        RK[tid] = r;
        gtab[r] = tk;        // sorted breakpoint table (scatter by rank)
        STl[r] = tk;         // LDS copy for LUT build
    }
    __syncthreads();
    if (tid <= 128) {
        int si = tid;
        float slS = 0, inS = 0, slT = 0, inT = 0;
        for (int k = 0; k < 128; ++k) {
            float w = W[k];
            if (w == 0.f) {
                float rb = fmaxf(Bb[k], 0.f);
                inS += rb * U[k];
                inT += rb * Vv[k];
            } else {
                bool act = (w > 0.f) ? (RK[k] < si) : (RK[k] >= si);
                if (act) {
                    slS += w * U[k];  inS += Bb[k] * U[k];
                    slT += w * Vv[k]; inT += Bb[k] * Vv[k];
                }
            }
        }
        gtab[128 + si] = slS;
        gtab[257 + si] = inS;
        gtab[386 + si] = slT;
        gtab[515 + si] = inT;
    }
}

// count of sorted breakpoints <= c over LDS array of 128
__device__ __forceinline__ int bsearch128(const float* T, float c) {
    int lo = 0, hi = 128;
    while (lo < hi) { int mid = (lo + hi) >> 1; if (T[mid] <= c) lo = mid + 1; else hi = mid; }
    return lo;
}

// ---------------------------------------------------------------------------
// Phase 0: input instance-norm stats (512 cols, 1/block); block 128 = scalar
// constants; blocks 129/130 = dist/angle piecewise tables + bucket LUTs.
template <typename T>
__device__ void phase0(const KP& p, float* st, float* smem) {
    float* scr = smem + 2560;
    int cid = blockIdx.x;    // 0..511
    int tid = threadIdx.x;
    {
        int which = cid >> 8, b = (cid >> 7) & 1, d = cid & 127;
        const T* src = (const T*)(which ? p.col : p.row) + (size_t)b * Nn * Dn + d;
        float x0 = cvt(src[(size_t)tid * Dn]);
        float x1 = cvt(src[(size_t)(tid + 256) * Dn]);
        float s = x0 + x1, ss = x0 * x0 + x1 * x1;
        blk_sum2(s, ss, scr);
        if (tid == 0) {
            float m = s * (1.f / Nn);
            float v = fmaxf(ss * (1.f / Nn) - m * m, 0.f);
            float rstd = rsqrtf(v + 1e-5f);
            const T* w = which ? (const T*)p.n2w : (const T*)p.n1w;
            const T* bb = which ? (const T*)p.n2b : (const T*)p.n1b;
            float sc = rstd * cvt(w[d]);
            st[ST_IN_SC + cid] = sc;
            st[ST_IN_SH + cid] = cvt(bb[d]) - m * sc;
        }
    }
    __syncthreads();
    if (cid == 128) {
        const T* db2 = (const T*)p.db2; const T* ab2 = (const T*)p.ab2;
        const T* ow = (const T*)p.ow;   const T* gw = (const T*)p.gw;
        float d2 = 0.f, a2 = 0.f, o = 0.f, g0 = 0.f, g1 = 0.f;
        if (tid < 128) {
            d2 = cvt(db2[tid]); a2 = cvt(ab2[tid]);
            o = cvt(ow[tid]); g0 = cvt(gw[tid]); g1 = cvt(gw[Dn + tid]);
        }
        float cds = d2 * o, cdt = d2 * g0, cas = a2 * o, cat = a2 * g1;
        blk_sum2(cds, cdt, scr);
        blk_sum2(cas, cat, scr);
        if (tid == 0) {
            float* pre = st + ST_PRE;
            pre[P_SC + 0] = cds; pre[P_SC + 1] = cdt;
            pre[P_SC + 2] = cas; pre[P_SC + 3] = cat;
            pre[P_SC + 4] = cvt(((const T*)p.gb)[0]);
            pre[P_SC + 5] = cvt(((const T*)p.ob)[0]);
            pre[P_SC + 6] = cvt(((const T*)p.alpha)[0]);
        }
    } else if (cid == 129) {
        build_tables<T>((const T*)p.dw1, (const T*)p.db1, (const T*)p.dw2,
                        (const T*)p.ow, (const T*)p.gw, st + ST_TAB, smem);
        __syncthreads();
        const float* STl = smem + 768;
        for (int e = tid; e < 257; e += 256) {
            float c = e * (1.f / 256.f);                 // cost domain [0,1]
            st[ST_LUTC + e] = (float)bsearch128(STl, c);
        }
    } else if (cid == 130) {
        build_tables<T>((const T*)p.aw1, (const T*)p.ab1, (const T*)p.aw2,
                        (const T*)p.ow, (const T*)p.gw + Dn, st + ST_TAB + TAB_ANG, smem);
        __syncthreads();
        const float* STl = smem + 768;
        for (int e = tid; e < 257; e += 256) {
            float a = -PI_F + e * (PI_F / 128.f);        // angle domain [-pi,pi]
            st[ST_LUTA + e] = (float)bsearch128(STl, a);
        }
    }
}

// ---------------------------------------------------------------------------
// Phase 1: QKV only. 4 rows/block, 512 threads, 256 blocks.
template <typename T>
__device__ void phase1(const KP& p, float* st, float* smem) {
    int tid = threadIdx.x;
    int r0 = blockIdx.x * 4;     // rows r0..r0+3 (0..1023)
    int b = r0 >> 9;
    const T* row = (const T*)p.row; const T* col = (const T*)p.col;
    float* ws = p.ws;
    float* Q = ws + WS_Q; float* Kraw = ws + WS_K; float* V = ws + WS_V;

    float* lr = smem;            // [4][128]
    float* lc = smem + 512;      // [4][128]
    float* redq = smem + 1024;   // [4(q)][4(r)][128]
    float* redk = smem + 3072;
    float* redv = smem + 5120;
    {
        int r = tid >> 7, d = tid & 127;
        float scR = st[ST_IN_SC + b * 128 + d],       shR = st[ST_IN_SH + b * 128 + d];
        float scC = st[ST_IN_SC + 256 + b * 128 + d], shC = st[ST_IN_SH + 256 + b * 128 + d];
        lr[r * 128 + d] = cvt(row[(size_t)(r0 + r) * Dn + d]) * scR + shR;
        lc[r * 128 + d] = cvt(col[(size_t)(r0 + r) * Dn + d]) * scC + shC;
    }
    __syncthreads();
    {
        int h = tid & 127, q = tid >> 7;
        const T* qw = (const T*)p.qw; const T* kw = (const T*)p.kw; const T* vw = (const T*)p.vw;
        float aq[4] = {0,0,0,0}, ak[4] = {0,0,0,0}, av[4] = {0,0,0,0};
        int ks = q * 32;
#pragma unroll 8
        for (int k = ks; k < ks + 32; ++k) {
            float wq = cvt(qw[k * Dn + h]);
            float wk = cvt(kw[k * Dn + h]);
            float wv = cvt(vw[k * Dn + h]);
#pragma unroll
            for (int r = 0; r < 4; ++r) {
                aq[r] += lr[r * 128 + k] * wq;
                ak[r] += lc[r * 128 + k] * wk;
                av[r] += lc[r * 128 + k] * wv;
            }
        }
#pragma unroll
        for (int r = 0; r < 4; ++r) {
            redq[q * 512 + r * 128 + h] = aq[r];
            redk[q * 512 + r * 128 + h] = ak[r];
            redv[q * 512 + r * 128 + h] = av[r];
        }
    }
    __syncthreads();
    if (tid < 128) {
        int h = tid;
        float bq = cvt(((const T*)p.qb)[h]);
        float bk = cvt(((const T*)p.kb)[h]);
        float bv = cvt(((const T*)p.vb)[h]);
#pragma unroll
        for (int r = 0; r < 4; ++r) {
            float qv = redq[r*128+h] + redq[512 + r*128+h] + redq[1024 + r*128+h] + redq[1536 + r*128+h] + bq;
            float kv = redk[r*128+h] + redk[512 + r*128+h] + redk[1024 + r*128+h] + redk[1536 + r*128+h] + bk;
            float vv = redv[r*128+h] + redv[512 + r*128+h] + redv[1024 + r*128+h] + redv[1536 + r*128+h] + bv;
            Q[(r0 + r) * Dn + h]    = sigmoidf_(qv);
            Kraw[(r0 + r) * Dn + h] = kv;
            V[(r0 + r) * Dn + h]    = vv;
        }
    }
}

// ---------------------------------------------------------------------------
// Phase 2: K-softmax over tokens + fused eK/eKV, [j][h] layout. 256 blocks x 256 thr.
// Computed ONCE here (R4 lesson: recomputing per attn-block multiplies exp work 128x).
__device__ void phase2(const KP& p, float* smem) {
    float* scr = smem + 2560;
    int tid = threadIdx.x;
    int c = blockIdx.x;          // 0..255
    int b = c >> 7, h = c & 127;
    float* ws = p.ws;
    const float* Kraw = ws + WS_K;
    const float* V = ws + WS_V;
    float* eK = ws + WS_EK;
    float* eKV = ws + WS_EKV;
    const float* kb = Kraw + (size_t)b * Nn * Dn + h;
    const float* vb = V + (size_t)b * Nn * Dn + h;
    float x0 = kb[(size_t)tid * Dn];
    float x1 = kb[(size_t)(tid + 256) * Dn];
    float mx = blk_max1(fmaxf(x0, x1), scr);
    float e0 = __expf(x0 - mx), e1 = __expf(x1 - mx);
    float s = blk_sum1(e0 + e1, scr);
    float rs = 1.f / s;
    size_t a0 = (size_t)b * Nn * Dn + (size_t)tid * Dn + h;
    size_t a1 = (size_t)b * Nn * Dn + (size_t)(tid + 256) * Dn + h;
    float ek0 = __expf(e0 * rs), ek1 = __expf(e1 * rs);
    eK[a0] = ek0;  eKV[a0] = ek0 * vb[(size_t)tid * Dn];
    eK[a1] = ek1;  eKV[a1] = ek1 * vb[(size_t)(tid + 256) * Dn];
}

// ---------------------------------------------------------------------------
// Phase 3 (fused): eab inline (4 rows, LDS-only) + num/den from precomputed
// eK/eKV + p/mhc projections. 256 blocks x 512 thr.
// LDS: ab[2048] | redn[2048] | redd[2048] | gl[512] | yl[512] | scr[64]
//      tab+luts [1802] overlaid on redn during eab step.
template <typename T>
__device__ void phase3(const KP& p, float* st, float* smem) {
    int tid = threadIdx.x;
    int r0 = blockIdx.x * 4;
    int b = r0 >> 9;
    float* ws = p.ws;
    const float* eK = ws + WS_EK;
    const float* eKV = ws + WS_EKV;
    const float* Q = ws + WS_Q;
    float* mh = ws + WS_MH;

    float* ab   = smem;          // 2048
    float* redn = smem + 2048;   // 2048
    float* redd = smem + 4096;   // 2048
    float* gl   = smem + 6144;   // 512
    float* yl   = smem + 6656;   // 512
    float* scr  = smem + 7168;   // 64

    // ---- step 1: eab for rows r0..r0+3, one j per thread, into ab[] ----
    {
        float* tab  = smem + 2048;   // [1288] overlays redn
        float* lutc = smem + 3336;   // [257]
        float* luta = smem + 3593;   // [257]  (ends 3850 < 4096)
        const float* gt = st + ST_TAB;
        for (int e = tid; e < TABLUT_N; e += 512) tab[e] = gt[e];
        __syncthreads();
        const float* pre = st + ST_PRE;
        float cds = pre[P_SC + 0], cdt = pre[P_SC + 1], cas = pre[P_SC + 2], cat = pre[P_SC + 3];
        float gbias = pre[P_SC + 4], obias = pre[P_SC + 5], alpha = pre[P_SC + 6];
        const T* cost = (const T*)p.cost;
        const T* coords = (const T*)p.coords;
        const float* tabA = tab + TAB_ANG;

        int j = tid;
        float cjx = cvt(coords[((size_t)b * Nn + j) * 2 + 0]);
        float cjy = cvt(coords[((size_t)b * Nn + j) * 2 + 1]);
        float av[4];
#pragma unroll
        for (int rr = 0; rr < 4; ++rr) {
            int i = (r0 + rr) & 511;
            float cix = cvt(coords[((size_t)b * Nn + i) * 2 + 0]);
            float ciy = cvt(coords[((size_t)b * Nn + i) * 2 + 1]);
            float c = cvt(cost[(size_t)b * Nn * Nn + (size_t)i * Nn + j]);
            int k = (int)(c * 256.f); k = k < 0 ? 0 : (k > 255 ? 255 : k);
            int lo = (int)lutc[k], hi = (int)lutc[k + 1];
            while (lo < hi && tab[lo] <= c) ++lo;
            float sd = fmaf(tab[128 + lo], c, tab[257 + lo]) + cds;
            float td = fmaf(tab[386 + lo], c, tab[515 + lo]) + cdt;
            float dx = cix - cjx;
            float dy = ciy - cjy;
            float ang = (dx == 0.f && dy == 0.f) ? 0.f : fatan2f(dy, dx);
            int ka = (int)((ang + PI_F) * (128.f / PI_F)); ka = ka < 0 ? 0 : (ka > 255 ? 255 : ka);
            int la = (int)luta[ka], ha = (int)luta[ka + 1];
            while (la < ha && tabA[la] <= ang) ++la;
            float sa = fmaf(tabA[128 + la], ang, tabA[257 + la]) + cas;
            float ta = fmaf(tabA[386 + la], ang, tabA[515 + la]) + cat;
            float gv = sigmoidf_(td + ta + gbias);
            av[rr] = alpha * (gv * sd + (1.f - gv) * sa + obias);
        }
        // per-row softmax over 512 (register + scr), then store exp(e*rs) to ab
        int wave = tid >> 6, lane = tid & 63;
        float t0 = av[0], t1 = av[1], t2 = av[2], t3 = av[3];
#pragma unroll
        for (int off = 32; off > 0; off >>= 1) {
            t0 = fmaxf(t0, __shfl_down(t0, off));
            t1 = fmaxf(t1, __shfl_down(t1, off));
            t2 = fmaxf(t2, __shfl_down(t2, off));
            t3 = fmaxf(t3, __shfl_down(t3, off));
        }
        __syncthreads();   // also fences tab reads before scr use
        if (lane == 0) { scr[wave] = t0; scr[8 + wave] = t1; scr[16 + wave] = t2; scr[24 + wave] = t3; }
        __syncthreads();
        float ev[4];
#pragma unroll
        for (int rr = 0; rr < 4; ++rr) {
            float m = scr[rr * 8];
#pragma unroll
            for (int w = 1; w < 8; ++w) m = fmaxf(m, scr[rr * 8 + w]);
            ev[rr] = __expf(av[rr] - m);
        }
        float s0 = ev[0], s1 = ev[1], s2 = ev[2], s3 = ev[3];
#pragma unroll
        for (int off = 32; off > 0; off >>= 1) {
            s0 += __shfl_down(s0, off);
            s1 += __shfl_down(s1, off);
            s2 += __shfl_down(s2, off);
            s3 += __shfl_down(s3, off);
        }
        if (lane == 0) { scr[32 + wave] = s0; scr[40 + wave] = s1; scr[48 + wave] = s2; scr[56 + wave] = s3; }
        __syncthreads();
#pragma unroll
        for (int rr = 0; rr < 4; ++rr) {
            float s = 0.f;
#pragma unroll
            for (int w = 0; w < 8; ++w) s += scr[32 + rr * 8 + w];
            ab[rr * 512 + j] = __expf(ev[rr] / s);
        }
    }
    __syncthreads();   // ab complete; tab region free for redn reuse

    int h = tid & 127, q = tid >> 7;   // q in 0..3
    int j0 = q * 128;

    // ---- step 2: num/den from precomputed eK/eKV ----
    {
        const float* ekb = eK + (size_t)b * Nn * Dn + h;
        const float* evb = eKV + (size_t)b * Nn * Dn + h;
        float num[4] = {0,0,0,0}, den[4] = {0,0,0,0};
#pragma unroll 4
        for (int j = j0; j < j0 + 128; ++j) {
            float ek = ekb[(size_t)j * Dn];
            float ev_ = evb[(size_t)j * Dn];
#pragma unroll
            for (int r = 0; r < 4; ++r) {
                num[r] += ab[r * 512 + j] * ev_;
                den[r] += ab[r * 512 + j] * ek;
            }
        }
#pragma unroll
        for (int r = 0; r < 4; ++r) {
            redn[q * 512 + r * 128 + h] = num[r];
            redd[q * 512 + r * 128 + h] = den[r];
        }
    }
    __syncthreads();
    if (tid < 128) {
#pragma unroll
        for (int r = 0; r < 4; ++r) {
            float nu = redn[r * 128 + h] + redn[512 + r * 128 + h]
                     + redn[1024 + r * 128 + h] + redn[1536 + r * 128 + h];
            float de = redd[r * 128 + h] + redd[512 + r * 128 + h]
                     + redd[1024 + r * 128 + h] + redd[1536 + r * 128 + h];
            gl[r * 128 + h] = Q[(r0 + r) * Dn + h] * nu / de;
        }
    }
    __syncthreads();
    {   // Yt = G@pw + pb : k-quarter of 32
        const T* pw = (const T*)p.pw;
        float acc[4] = {0,0,0,0};
        int ks = q * 32;
#pragma unroll 8
        for (int k = ks; k < ks + 32; ++k) {
            float w = cvt(pw[k * Dn + h]);
#pragma unroll
            for (int r = 0; r < 4; ++r) acc[r] += gl[r * 128 + k] * w;
        }
#pragma unroll
        for (int r = 0; r < 4; ++r) redn[q * 512 + r * 128 + h] = acc[r];
    }
    __syncthreads();
    if (tid < 128) {
        float bp = cvt(((const T*)p.pb)[h]);
#pragma unroll
        for (int r = 0; r < 4; ++r)
            yl[r * 128 + h] = redn[r * 128 + h] + redn[512 + r * 128 + h]
                            + redn[1024 + r * 128 + h] + redn[1536 + r * 128 + h] + bp;
    }
    __syncthreads();
    {   // mh = Yt@mw + mb
        const T* mw = (const T*)p.mw;
        float acc[4] = {0,0,0,0};
        int ks = q * 32;
#pragma unroll 8
        for (int k = ks; k < ks + 32; ++k) {
            float w = cvt(mw[k * Dn + h]);
#pragma unroll
            for (int r = 0; r < 4; ++r) acc[r] += yl[r * 128 + k] * w;
        }
#pragma unroll
        for (int r = 0; r < 4; ++r) redn[q * 512 + r * 128 + h] = acc[r];
    }
    __syncthreads();
    if (tid < 128) {
        float bm = cvt(((const T*)p.mb)[h]);
#pragma unroll
        for (int r = 0; r < 4; ++r)
            mh[(r0 + r) * Dn + h] = redn[r * 128 + h] + redn[512 + r * 128 + h]
                                  + redn[1024 + r * 128 + h] + redn[1536 + r * 128 + h] + bm;
    }
}

// ---------------------------------------------------------------------------
// Phase 4+5 fused: per-column mh stats (local) -> t build -> x stats. 256 blocks.
template <typename T>
__device__ void phase45(const KP& p, float* st, float* smem) {
    float* scr = smem + 2560;
    int tid = threadIdx.x;
    int c = blockIdx.x;          // 0..255
    int b = c >> 7, d = c & 127;
    const float* mh = p.ws + WS_MH;
    const float* mp = mh + (size_t)b * Nn * Dn + d;
    float m0 = mp[(size_t)tid * Dn], m1 = mp[(size_t)(tid + 256) * Dn];
    float s = m0 + m1, ss = m0 * m0 + m1 * m1;
    blk_sum2(s, ss, scr);
    float mm = s * (1.f / Nn);
    float vv = fmaxf(ss * (1.f / Nn) - mm * mm, 0.f);
    float rstd = rsqrtf(vv + 1e-5f);
    float scM = rstd * cvt(((const T*)p.n3w)[d]);
    float shM = cvt(((const T*)p.n3b)[d]) - mm * scM;
    const T* row = (const T*)p.row;
    float scI = st[ST_IN_SC + c], shI = st[ST_IN_SH + c];
    const T* rp = row + (size_t)b * Nn * Dn + d;
    float* tp = p.ws + WS_T + (size_t)b * Nn * Dn + d;
    float x0 = cvt(rp[(size_t)tid * Dn]) * scI + shI + m0 * scM + shM;
    float x1 = cvt(rp[(size_t)(tid + 256) * Dn]) * scI + shI + m1 * scM + shM;
    tp[(size_t)tid * Dn] = x0;
    tp[(size_t)(tid + 256) * Dn] = x1;
    __syncthreads();
    float s2 = x0 + x1, ss2 = x0 * x0 + x1 * x1;
    blk_sum2(s2, ss2, scr);
    if (tid == 0) {
        float m = s2 * (1.f / Nn);
        float v = fmaxf(ss2 * (1.f / Nn) - m * m, 0.f);
        float r = rsqrtf(v + 1e-5f);
        float sc = r * cvt(((const T*)p.f1w)[d]);
        st[ST_X_SC + c] = sc;
        st[ST_X_SH + c] = cvt(((const T*)p.f1b)[d]) - m * sc;
    }
}

// ---------------------------------------------------------------------------
// Phase 6: FFN (x normalized inline). 4 rows/block, 512 threads, 256 blocks.
template <typename T>
__device__ void phase6(const KP& p, float* st, float* smem) {
    int tid = threadIdx.x;
    int r0 = blockIdx.x * 4;
    int b = r0 >> 9;
    const float* t = p.ws + WS_T;
    float* outpre = p.ws + WS_OP;
    const T* w1 = (const T*)p.ffw1; const T* b1 = (const T*)p.ffb1;
    const T* w2 = (const T*)p.ffw2; const T* b2 = (const T*)p.ffb2;

    float* xl = smem;            // [4][128] = 512
    float* hl = smem + 512;      // [4][512] = 2048
    float* red = smem + 2560;    // [4(q)][4(r)][128] = 2048
    {
        int r = tid >> 7, d = tid & 127;
        int c = b * 128 + d;
        xl[r * 128 + d] = t[(r0 + r) * Dn + d] * st[ST_X_SC + c] + st[ST_X_SH + c];
    }
    __syncthreads();
    {
        int f = tid;
        float a[4] = {0,0,0,0};
#pragma unroll 4
        for (int k = 0; k < Dn; ++k) {
            float w = cvt(w1[k * FHn + f]);
#pragma unroll
            for (int r = 0; r < 4; ++r) a[r] += xl[r * 128 + k] * w;
        }
        float bb1 = cvt(b1[f]);
#pragma unroll
        for (int r = 0; r < 4; ++r) hl[r * 512 + f] = fmaxf(a[r] + bb1, 0.f);
    }
    __syncthreads();
    {
        int d = tid & 127, q = tid >> 7;
        int k0 = q * 128;
        float a[4] = {0,0,0,0};
#pragma unroll 8
        for (int k = k0; k < k0 + 128; ++k) {
            float w = cvt(w2[k * Dn + d]);
#pragma unroll
            for (int r = 0; r < 4; ++r) a[r] += hl[r * 512 + k] * w;
        }
#pragma unroll
        for (int r = 0; r < 4; ++r) red[q * 512 + r * 128 + d] = a[r];
    }
    __syncthreads();
    if (tid < 128) {
        float bb2 = cvt(b2[tid]);
#pragma unroll
        for (int r = 0; r < 4; ++r) {
            float sum = red[r * 128 + tid] + red[512 + r * 128 + tid]
                      + red[1024 + r * 128 + tid] + red[1536 + r * 128 + tid];
            outpre[(r0 + r) * Dn + tid] = xl[r * 128 + tid] + sum + bb2;
        }
    }
}

// ---------------------------------------------------------------------------
// Phase 7+8 fused: per-column outpre stats (local) -> cast out. 256 blocks.
template <typename T>
__device__ void phase78(const KP& p, float* smem) {
    float* scr = smem + 2560;
    int tid = threadIdx.x;
    int c = blockIdx.x;          // 0..255
    int b = c >> 7, d = c & 127;
    const float* op = p.ws + WS_OP;
    const float* sp = op + (size_t)b * Nn * Dn + d;
    float x0 = sp[(size_t)tid * Dn], x1 = sp[(size_t)(tid + 256) * Dn];
    float s = x0 + x1, ss = x0 * x0 + x1 * x1;
    blk_sum2(s, ss, scr);
    float m = s * (1.f / Nn);
    float v = fmaxf(ss * (1.f / Nn) - m * m, 0.f);
    float rstd = rsqrtf(v + 1e-5f);
    float sc = rstd * cvt(((const T*)p.f2w)[d]);
    float sh = cvt(((const T*)p.f2b)[d]) - m * sc;
    T* out = (T*)p.out + (size_t)b * Nn * Dn + d;
    out[(size_t)tid * Dn] = (T)(x0 * sc + sh);
    out[(size_t)(tid + 256) * Dn] = (T)(x1 * sc + sh);
}

// ---------------------------------------------------------------------------
// Kernel wrappers
#define PH_WRAP(name, call_bf, call_f)                                        \
__global__ __launch_bounds__(256) void name(KP p) {                           \
    __shared__ float smem[SMEM_FLOATS];                                       \
    float* st = p.ws + WS_ST; (void)st;                                       \
    if (is_bf16(p.alpha)) { call_bf; } else { call_f; }                       \
}

PH_WRAP(k_head,  phase0<bf16>(p, st, smem),  phase0<float>(p, st, smem))
__global__ __launch_bounds__(512) void k_qkv(KP p) {
    __shared__ float smem[7168];
    float* st = p.ws + WS_ST;
    if (is_bf16(p.alpha)) phase1<bf16>(p, st, smem);
    else                  phase1<float>(p, st, smem);
}
__global__ __launch_bounds__(256) void k_kekv(KP p) {
    __shared__ float smem[SMEM_FLOATS];
    phase2(p, smem);
}
__global__ __launch_bounds__(512) void k_attn(KP p) {
    __shared__ float smem[7232];   // 28.9 KB
    float* st = p.ws + WS_ST;
    if (is_bf16(p.alpha)) phase3<bf16>(p, st, smem);
    else                  phase3<float>(p, st, smem);
}
PH_WRAP(k_mid,   phase45<bf16>(p, st, smem), phase45<float>(p, st, smem))
__global__ __launch_bounds__(512) void k_ffn(KP p) {
    __shared__ float smem[4608];   // 18 KB
    float* st = p.ws + WS_ST;
    if (is_bf16(p.alpha)) phase6<bf16>(p, st, smem);
    else                  phase6<float>(p, st, smem);
}
PH_WRAP(k_tail,  phase78<bf16>(p, smem),     phase78<float>(p, smem))

// ---------------------------------------------------------------------------
extern "C" void kernel_launch(void* const* d_in, const int* in_sizes, int n_in,
                              void* d_out, int out_size, void* d_ws, size_t ws_size,
                              hipStream_t stream) {
    KP p;
    p.row = d_in[0];  p.col = d_in[1];  p.cost = d_in[2];  p.coords = d_in[3];
    p.alpha = d_in[4];
    p.n1w = d_in[5];  p.n1b = d_in[6];  p.n2w = d_in[7];  p.n2b = d_in[8];
    p.n3w = d_in[9];  p.n3b = d_in[10]; p.f1w = d_in[11]; p.f1b = d_in[12];
    p.f2w = d_in[13]; p.f2b = d_in[14];
    p.qw = d_in[15];  p.qb = d_in[16];  p.kw = d_in[17];  p.kb = d_in[18];
    p.vw = d_in[19];  p.vb = d_in[20];  p.pw = d_in[21];  p.pb = d_in[22];
    p.mw = d_in[23];  p.mb = d_in[24];
    p.dw1 = d_in[25]; p.db1 = d_in[26]; p.dw2 = d_in[27]; p.db2 = d_in[28];
    p.aw1 = d_in[29]; p.ab1 = d_in[30]; p.aw2 = d_in[31]; p.ab2 = d_in[32];
    p.gw = d_in[33];  p.gb = d_in[34];  p.ow = d_in[35];  p.ob = d_in[36];
    p.ffw1 = d_in[37]; p.ffb1 = d_in[38]; p.ffw2 = d_in[39]; p.ffb2 = d_in[40];
    p.out = d_out;
    p.ws = (float*)d_ws;

    k_head<<<512, 256, 0, stream>>>(p);
    k_qkv<<<256, 512, 0, stream>>>(p);
    k_kekv<<<256, 256, 0, stream>>>(p);
    k_attn<<<256, 512, 0, stream>>>(p);
    k_mid<<<256, 256, 0, stream>>>(p);
    k_ffn<<<256, 512, 0, stream>>>(p);
    k_tail<<<256, 256, 0, stream>>>(p);
}

// Round 6
// 230.550 us; speedup vs baseline: 1.0988x; 1.0041x over previous
//
#include <hip/hip_runtime.h>
#include <hip/hip_bf16.h>
#include <math.h>

// Problem constants
#define Bn  2
#define Nn  512
#define Dn  128
#define FHn 512

#define PI_F 3.14159265358979323846f

typedef __hip_bfloat16 bf16;

__device__ __forceinline__ float cvt(float x) { return x; }
__device__ __forceinline__ float cvt(bf16 x) { return __bfloat162float(x); }
__device__ __forceinline__ float sigmoidf_(float x) { return 1.0f / (1.0f + __expf(-x)); }
__device__ __forceinline__ bool is_bf16(const void* alpha) {
    return ((const unsigned short*)alpha)[0] == 0x3F80;
}

// fast atan2, max abs err ~2e-5 rad (output guaranteed in [-pi, pi])
__device__ __forceinline__ float fatan2f(float dy, float dx) {
    float ax = fabsf(dx), ay = fabsf(dy);
    float mx = fmaxf(ax, ay), mn = fminf(ax, ay);
    float r = __fdividef(mn, mx);
    float t = r * r;
    float a = r * (0.99997726f + t * (-0.33262347f + t * (0.19354346f +
              t * (-0.11643287f + t * (0.05265332f + t * (-0.01172120f))))));
    if (ay > ax) a = 1.57079632679489662f - a;
    if (dx < 0.f) a = PI_F - a;
    if (dy < 0.f) a = -a;
    return fminf(fmaxf(a, -PI_F), PI_F);
}

// ---------------------------------------------------------------------------
// Workspace layout (float offsets). S = one (B,N,D) f32 slab.
#define S_ 131072
#define WS_Q    (0 * S_)
#define WS_K    (1 * S_)
#define WS_V    (2 * S_)
#define WS_EK   (3 * S_)
#define WS_EKV  (4 * S_)
#define WS_MH   (5 * S_)
#define WS_T    (6 * S_)
#define WS_OP   (7 * S_)
#define WS_ST   (8 * S_)

// stats region (float offsets inside WS_ST)
#define ST_IN_SC   0      // 512: [which*256 + b*128 + d]
#define ST_IN_SH   512
#define ST_X_SC    2048
#define ST_X_SH    2304
#define ST_PRE     3072
#define P_SC       1024   // cds, cdt, cas, cat, gate_b, outlin_b, alpha (7)
#define ST_TAB     4224   // 1288 floats of piecewise-linear tables
#define TAB_ANG 644
#define TAB_N   1288
// bucket->segment LUTs (257 each), contiguous right after the tables
#define ST_LUTC (ST_TAB + TAB_N)        // 5512
#define ST_LUTA (ST_LUTC + 257)         // 5769
#define TABLUT_N (TAB_N + 514)          // 1802 contiguous floats

#define SMEM_FLOATS 2568   // 2560 work + 8 reduce scratch (256-thread kernels)

struct KP {
    const void *row, *col, *cost, *coords, *alpha;
    const void *n1w, *n1b, *n2w, *n2b, *n3w, *n3b, *f1w, *f1b, *f2w, *f2b;
    const void *qw, *qb, *kw, *kb, *vw, *vb, *pw, *pb, *mw, *mb;
    const void *dw1, *db1, *dw2, *db2, *aw1, *ab1, *aw2, *ab2, *gw, *gb, *ow, *ob;
    const void *ffw1, *ffb1, *ffw2, *ffb2;
    void* out;
    float* ws;
};

// ---------------------------------------------------------------------------
// Block-level reductions (256 threads). scr >= 8 floats. All threads get result.
__device__ __forceinline__ void blk_sum2(float& s, float& ss, volatile float* scr) {
#pragma unroll
    for (int off = 32; off > 0; off >>= 1) { s += __shfl_down(s, off); ss += __shfl_down(ss, off); }
    __syncthreads();
    int wave = threadIdx.x >> 6, lane = threadIdx.x & 63;
    if (lane == 0) { scr[wave] = s; scr[4 + wave] = ss; }
    __syncthreads();
    s = scr[0] + scr[1] + scr[2] + scr[3];
    ss = scr[4] + scr[5] + scr[6] + scr[7];
}

// 512-thread block reductions (R2-verified). scr >= 16 floats.
__device__ __forceinline__ void blk512_sum2(float& s, float& ss, volatile float* scr) {
#pragma unroll
    for (int off = 32; off > 0; off >>= 1) { s += __shfl_down(s, off); ss += __shfl_down(ss, off); }
    __syncthreads();
    int wave = threadIdx.x >> 6, lane = threadIdx.x & 63;
    if (lane == 0) { scr[wave] = s; scr[8 + wave] = ss; }
    __syncthreads();
    s = 0.f; ss = 0.f;
#pragma unroll
    for (int w = 0; w < 8; ++w) { s += scr[w]; ss += scr[8 + w]; }
}

__device__ __forceinline__ float blk512_sum1(float v, volatile float* scr) {
#pragma unroll
    for (int off = 32; off > 0; off >>= 1) v += __shfl_down(v, off);
    __syncthreads();
    int wave = threadIdx.x >> 6, lane = threadIdx.x & 63;
    if (lane == 0) scr[wave] = v;
    __syncthreads();
    float s = 0.f;
#pragma unroll
    for (int w = 0; w < 8; ++w) s += scr[w];
    return s;
}

__device__ __forceinline__ float blk512_max1(float v, volatile float* scr) {
#pragma unroll
    for (int off = 32; off > 0; off >>= 1) v = fmaxf(v, __shfl_down(v, off));
    __syncthreads();
    int wave = threadIdx.x >> 6, lane = threadIdx.x & 63;
    if (lane == 0) scr[wave] = v;
    __syncthreads();
    float m = scr[0];
#pragma unroll
    for (int w = 1; w < 8; ++w) m = fmaxf(m, scr[w]);
    return m;
}

// ---------------------------------------------------------------------------
// Build piecewise-linear tables for one scalar MLP — fully parallel.
// Also leaves the SORTED breakpoints in smem+768 (128 floats) for LUT build.
template <typename T>
__device__ void build_tables(const T* w1p, const T* b1p, const T* w2p,
                             const T* owp, const T* gwp, float* gtab, float* smem) {
    int tid = threadIdx.x;
    float* W  = smem;          // 128
    float* Bb = smem + 128;
    float* U  = smem + 256;
    float* Vv = smem + 384;
    float* Tt = smem + 512;
    int* RK   = (int*)(smem + 640);   // 128 ranks
    float* STl = smem + 768;          // sorted breakpoints (LDS copy)
    if (tid < 128) {
        float u = 0.f, v = 0.f;
#pragma unroll 4
        for (int d = 0; d < Dn; ++d) {
            float w2 = cvt(w2p[tid * Dn + d]);
            u += w2 * cvt(owp[d]);
            v += w2 * cvt(gwp[d]);
        }
        float w = cvt(w1p[tid]), b = cvt(b1p[tid]);
        U[tid] = u; Vv[tid] = v; W[tid] = w; Bb[tid] = b;
        Tt[tid] = (w != 0.f) ? (-b / w) : 3.0e38f;
    }
    __syncthreads();
    if (tid < 128) {
        float tk = Tt[tid]; int r = 0;
        for (int j = 0; j < 128; ++j) {
            float tj = Tt[j];
            r += (tj < tk) || (tj == tk && j < tid);
        }
        RK[tid] = r;
        gtab[r] = tk;        // sorted breakpoint table (scatter by rank)
        STl[r] = tk;         // LDS copy for LUT build
    }
    __syncthreads();
    if (tid <= 128) {
        int si = tid;
        float slS = 0, inS = 0, slT = 0, inT = 0;
        for (int k = 0; k < 128; ++k) {
            float w = W[k];
            if (w == 0.f) {
                float rb = fmaxf(Bb[k], 0.f);
                inS += rb * U[k];
                inT += rb * Vv[k];
            } else {
                bool act = (w > 0.f) ? (RK[k] < si) : (RK[k] >= si);
                if (act) {
                    slS += w * U[k];  inS += Bb[k] * U[k];
                    slT += w * Vv[k]; inT += Bb[k] * Vv[k];
                }
            }
        }
        gtab[128 + si] = slS;
        gtab[257 + si] = inS;
        gtab[386 + si] = slT;
        gtab[515 + si] = inT;
    }
}

// count of sorted breakpoints <= c over LDS array of 128
__device__ __forceinline__ int bsearch128(const float* T, float c) {
    int lo = 0, hi = 128;
    while (lo < hi) { int mid = (lo + hi) >> 1; if (T[mid] <= c) lo = mid + 1; else hi = mid; }
    return lo;
}

// ---------------------------------------------------------------------------
// Phase 0: input instance-norm stats (512 cols, 1/block); block 128 = scalar
// constants; blocks 129/130 = dist/angle piecewise tables + bucket LUTs.
template <typename T>
__device__ void phase0(const KP& p, float* st, float* smem) {
    float* scr = smem + 2560;
    int cid = blockIdx.x;    // 0..511
    int tid = threadIdx.x;
    {
        int which = cid >> 8, b = (cid >> 7) & 1, d = cid & 127;
        const T* src = (const T*)(which ? p.col : p.row) + (size_t)b * Nn * Dn + d;
        float x0 = cvt(src[(size_t)tid * Dn]);
        float x1 = cvt(src[(size_t)(tid + 256) * Dn]);
        float s = x0 + x1, ss = x0 * x0 + x1 * x1;
        blk_sum2(s, ss, scr);
        if (tid == 0) {
            float m = s * (1.f / Nn);
            float v = fmaxf(ss * (1.f / Nn) - m * m, 0.f);
            float rstd = rsqrtf(v + 1e-5f);
            const T* w = which ? (const T*)p.n2w : (const T*)p.n1w;
            const T* bb = which ? (const T*)p.n2b : (const T*)p.n1b;
            float sc = rstd * cvt(w[d]);
            st[ST_IN_SC + cid] = sc;
            st[ST_IN_SH + cid] = cvt(bb[d]) - m * sc;
        }
    }
    __syncthreads();
    if (cid == 128) {
        const T* db2 = (const T*)p.db2; const T* ab2 = (const T*)p.ab2;
        const T* ow = (const T*)p.ow;   const T* gw = (const T*)p.gw;
        float d2 = 0.f, a2 = 0.f, o = 0.f, g0 = 0.f, g1 = 0.f;
        if (tid < 128) {
            d2 = cvt(db2[tid]); a2 = cvt(ab2[tid]);
            o = cvt(ow[tid]); g0 = cvt(gw[tid]); g1 = cvt(gw[Dn + tid]);
        }
        float cds = d2 * o, cdt = d2 * g0, cas = a2 * o, cat = a2 * g1;
        blk_sum2(cds, cdt, scr);
        blk_sum2(cas, cat, scr);
        if (tid == 0) {
            float* pre = st + ST_PRE;
            pre[P_SC + 0] = cds; pre[P_SC + 1] = cdt;
            pre[P_SC + 2] = cas; pre[P_SC + 3] = cat;
            pre[P_SC + 4] = cvt(((const T*)p.gb)[0]);
            pre[P_SC + 5] = cvt(((const T*)p.ob)[0]);
            pre[P_SC + 6] = cvt(((const T*)p.alpha)[0]);
        }
    } else if (cid == 129) {
        build_tables<T>((const T*)p.dw1, (const T*)p.db1, (const T*)p.dw2,
                        (const T*)p.ow, (const T*)p.gw, st + ST_TAB, smem);
        __syncthreads();
        const float* STl = smem + 768;
        for (int e = tid; e < 257; e += 256) {
            float c = e * (1.f / 256.f);                 // cost domain [0,1]
            st[ST_LUTC + e] = (float)bsearch128(STl, c);
        }
    } else if (cid == 130) {
        build_tables<T>((const T*)p.aw1, (const T*)p.ab1, (const T*)p.aw2,
                        (const T*)p.ow, (const T*)p.gw + Dn, st + ST_TAB + TAB_ANG, smem);
        __syncthreads();
        const float* STl = smem + 768;
        for (int e = tid; e < 257; e += 256) {
            float a = -PI_F + e * (PI_F / 128.f);        // angle domain [-pi,pi]
            st[ST_LUTA + e] = (float)bsearch128(STl, a);
        }
    }
}

// ---------------------------------------------------------------------------
// Phase 1: QKV only. 4 rows/block, 512 threads, 256 blocks.
template <typename T>
__device__ void phase1(const KP& p, float* st, float* smem) {
    int tid = threadIdx.x;
    int r0 = blockIdx.x * 4;     // rows r0..r0+3 (0..1023)
    int b = r0 >> 9;
    const T* row = (const T*)p.row; const T* col = (const T*)p.col;
    float* ws = p.ws;
    float* Q = ws + WS_Q; float* Kraw = ws + WS_K; float* V = ws + WS_V;

    float* lr = smem;            // [4][128]
    float* lc = smem + 512;      // [4][128]
    float* redq = smem + 1024;   // [4(q)][4(r)][128]
    float* redk = smem + 3072;
    float* redv = smem + 5120;
    {
        int r = tid >> 7, d = tid & 127;
        float scR = st[ST_IN_SC + b * 128 + d],       shR = st[ST_IN_SH + b * 128 + d];
        float scC = st[ST_IN_SC + 256 + b * 128 + d], shC = st[ST_IN_SH + 256 + b * 128 + d];
        lr[r * 128 + d] = cvt(row[(size_t)(r0 + r) * Dn + d]) * scR + shR;
        lc[r * 128 + d] = cvt(col[(size_t)(r0 + r) * Dn + d]) * scC + shC;
    }
    __syncthreads();
    {
        int h = tid & 127, q = tid >> 7;
        const T* qw = (const T*)p.qw; const T* kw = (const T*)p.kw; const T* vw = (const T*)p.vw;
        float aq[4] = {0,0,0,0}, ak[4] = {0,0,0,0}, av[4] = {0,0,0,0};
        int ks = q * 32;
#pragma unroll 8
        for (int k = ks; k < ks + 32; ++k) {
            float wq = cvt(qw[k * Dn + h]);
            float wk = cvt(kw[k * Dn + h]);
            float wv = cvt(vw[k * Dn + h]);
#pragma unroll
            for (int r = 0; r < 4; ++r) {
                aq[r] += lr[r * 128 + k] * wq;
                ak[r] += lc[r * 128 + k] * wk;
                av[r] += lc[r * 128 + k] * wv;
            }
        }
#pragma unroll
        for (int r = 0; r < 4; ++r) {
            redq[q * 512 + r * 128 + h] = aq[r];
            redk[q * 512 + r * 128 + h] = ak[r];
            redv[q * 512 + r * 128 + h] = av[r];
        }
    }
    __syncthreads();
    if (tid < 128) {
        int h = tid;
        float bq = cvt(((const T*)p.qb)[h]);
        float bk = cvt(((const T*)p.kb)[h]);
        float bv = cvt(((const T*)p.vb)[h]);
#pragma unroll
        for (int r = 0; r < 4; ++r) {
            float qv = redq[r*128+h] + redq[512 + r*128+h] + redq[1024 + r*128+h] + redq[1536 + r*128+h] + bq;
            float kv = redk[r*128+h] + redk[512 + r*128+h] + redk[1024 + r*128+h] + redk[1536 + r*128+h] + bk;
            float vv = redv[r*128+h] + redv[512 + r*128+h] + redv[1024 + r*128+h] + redv[1536 + r*128+h] + bv;
            Q[(r0 + r) * Dn + h]    = sigmoidf_(qv);
            Kraw[(r0 + r) * Dn + h] = kv;
            V[(r0 + r) * Dn + h]    = vv;
        }
    }
}

// ---------------------------------------------------------------------------
// Phase 2: K-softmax over tokens + fused eK/eKV, [j][h] layout.
// 256 blocks x 512 thr (1 token/thread; R2-verified body).
__device__ void phase2(const KP& p, float* smem) {
    float* scr = smem;           // 16 floats
    int tid = threadIdx.x;
    int c = blockIdx.x;          // 0..255
    int b = c >> 7, h = c & 127;
    float* ws = p.ws;
    const float* Kraw = ws + WS_K;
    const float* V = ws + WS_V;
    float* eK = ws + WS_EK;
    float* eKV = ws + WS_EKV;
    const float* kb = Kraw + (size_t)b * Nn * Dn + h;
    const float* vb = V + (size_t)b * Nn * Dn + h;
    float x0 = kb[(size_t)tid * Dn];
    float mx = blk512_max1(x0, scr);
    float e0 = __expf(x0 - mx);
    float s = blk512_sum1(e0, scr);
    float rs = 1.f / s;
    size_t a0 = (size_t)b * Nn * Dn + (size_t)tid * Dn + h;
    float ek0 = __expf(e0 * rs);
    eK[a0] = ek0;  eKV[a0] = ek0 * vb[(size_t)tid * Dn];
}

// ---------------------------------------------------------------------------
// Phase 3 (fused): eab inline + num/den from precomputed eK/eKV + p/mhc
// projections. 256 blocks x 1024 thr (16 waves/CU for latency hiding).
// LDS: ab[2048] | redn[4096] | redd[4096] | gl[512] | yl[512] | scr[64] = 11328
//      tab+luts [1802] overlaid on redn during eab step.
template <typename T>
__device__ void phase3(const KP& p, float* st, float* smem) {
    int tid = threadIdx.x;
    int r0 = blockIdx.x * 4;
    int b = r0 >> 9;
    float* ws = p.ws;
    const float* eK = ws + WS_EK;
    const float* eKV = ws + WS_EKV;
    const float* Q = ws + WS_Q;
    float* mh = ws + WS_MH;

    float* ab   = smem;          // 2048
    float* redn = smem + 2048;   // 4096
    float* redd = smem + 6144;   // 4096
    float* gl   = smem + 10240;  // 512
    float* yl   = smem + 10752;  // 512
    float* scr  = smem + 11264;  // 64

    // ---- step 1: eab for rows r0..r0+3; thread = (j = tid&511, row-pair) ----
    {
        float* tab  = smem + 2048;   // [1288] overlays redn
        float* lutc = smem + 3336;   // [257]
        float* luta = smem + 3593;   // [257]  (ends 3850 < 6144)
        const float* gt = st + ST_TAB;
        for (int e = tid; e < TABLUT_N; e += 1024) tab[e] = gt[e];
        __syncthreads();
        const float* pre = st + ST_PRE;
        float cds = pre[P_SC + 0], cdt = pre[P_SC + 1], cas = pre[P_SC + 2], cat = pre[P_SC + 3];
        float gbias = pre[P_SC + 4], obias = pre[P_SC + 5], alpha = pre[P_SC + 6];
        const T* cost = (const T*)p.cost;
        const T* coords = (const T*)p.coords;
        const float* tabA = tab + TAB_ANG;

        int j = tid & 511;
        int rp = tid >> 9;           // 0 or 1 -> rows 2rp, 2rp+1
        float cjx = cvt(coords[((size_t)b * Nn + j) * 2 + 0]);
        float cjy = cvt(coords[((size_t)b * Nn + j) * 2 + 1]);
        float av[2];
#pragma unroll
        for (int rr = 0; rr < 2; ++rr) {
            int row = rp * 2 + rr;
            int i = (r0 + row) & 511;
            float cix = cvt(coords[((size_t)b * Nn + i) * 2 + 0]);
            float ciy = cvt(coords[((size_t)b * Nn + i) * 2 + 1]);
            float c = cvt(cost[(size_t)b * Nn * Nn + (size_t)i * Nn + j]);
            int k = (int)(c * 256.f); k = k < 0 ? 0 : (k > 255 ? 255 : k);
            int lo = (int)lutc[k], hi = (int)lutc[k + 1];
            while (lo < hi && tab[lo] <= c) ++lo;
            float sd = fmaf(tab[128 + lo], c, tab[257 + lo]) + cds;
            float td = fmaf(tab[386 + lo], c, tab[515 + lo]) + cdt;
            float dx = cix - cjx;
            float dy = ciy - cjy;
            float ang = (dx == 0.f && dy == 0.f) ? 0.f : fatan2f(dy, dx);
            int ka = (int)((ang + PI_F) * (128.f / PI_F)); ka = ka < 0 ? 0 : (ka > 255 ? 255 : ka);
            int la = (int)luta[ka], ha = (int)luta[ka + 1];
            while (la < ha && tabA[la] <= ang) ++la;
            float sa = fmaf(tabA[128 + la], ang, tabA[257 + la]) + cas;
            float ta = fmaf(tabA[386 + la], ang, tabA[515 + la]) + cat;
            float gv = sigmoidf_(td + ta + gbias);
            av[rr] = alpha * (gv * sd + (1.f - gv) * sa + obias);
        }
        // per-row softmax over 512: row (2rp+rr)'s values live in waves rp*8..rp*8+7
        int wave = tid >> 6, lane = tid & 63, w8 = wave & 7;
        float t0 = av[0], t1 = av[1];
#pragma unroll
        for (int off = 32; off > 0; off >>= 1) {
            t0 = fmaxf(t0, __shfl_down(t0, off));
            t1 = fmaxf(t1, __shfl_down(t1, off));
        }
        __syncthreads();   // fences tab reads before scr use
        if (lane == 0) { scr[(rp * 2) * 8 + w8] = t0; scr[(rp * 2 + 1) * 8 + w8] = t1; }
        __syncthreads();
        float ev[2];
#pragma unroll
        for (int rr = 0; rr < 2; ++rr) {
            int row = rp * 2 + rr;
            float m = scr[row * 8];
#pragma unroll
            for (int w = 1; w < 8; ++w) m = fmaxf(m, scr[row * 8 + w]);
            ev[rr] = __expf(av[rr] - m);
        }
        float s0 = ev[0], s1 = ev[1];
#pragma unroll
        for (int off = 32; off > 0; off >>= 1) {
            s0 += __shfl_down(s0, off);
            s1 += __shfl_down(s1, off);
        }
        if (lane == 0) { scr[32 + (rp * 2) * 8 + w8] = s0; scr[32 + (rp * 2 + 1) * 8 + w8] = s1; }
        __syncthreads();
#pragma unroll
        for (int rr = 0; rr < 2; ++rr) {
            int row = rp * 2 + rr;
            float s = 0.f;
#pragma unroll
            for (int w = 0; w < 8; ++w) s += scr[32 + row * 8 + w];
            ab[row * 512 + j] = __expf(ev[rr] / s);
        }
    }
    __syncthreads();   // ab complete; tab region free for redn reuse

    int h = tid & 127, q = tid >> 7;   // q in 0..7 (64-j eighths)
    int j0 = q * 64;

    // ---- step 2: num/den from precomputed eK/eKV ----
    {
        const float* ekb = eK + (size_t)b * Nn * Dn + h;
        const float* evb = eKV + (size_t)b * Nn * Dn + h;
        float num[4] = {0,0,0,0}, den[4] = {0,0,0,0};
#pragma unroll 4
        for (int j = j0; j < j0 + 64; ++j) {
            float ek = ekb[(size_t)j * Dn];
            float ev_ = evb[(size_t)j * Dn];
#pragma unroll
            for (int r = 0; r < 4; ++r) {
                num[r] += ab[r * 512 + j] * ev_;
                den[r] += ab[r * 512 + j] * ek;
            }
        }
#pragma unroll
        for (int r = 0; r < 4; ++r) {
            redn[q * 512 + r * 128 + h] = num[r];
            redd[q * 512 + r * 128 + h] = den[r];
        }
    }
    __syncthreads();
    if (tid < 512) {
        int r = tid >> 7;   // (r, h) pair
        float nu = 0.f, de = 0.f;
#pragma unroll
        for (int qq = 0; qq < 8; ++qq) {
            nu += redn[qq * 512 + r * 128 + h];
            de += redd[qq * 512 + r * 128 + h];
        }
        gl[r * 128 + h] = Q[(r0 + r) * Dn + h] * nu / de;
    }
    __syncthreads();
    if (tid < 512) {   // Yt = G@pw + pb : full dot per (r,h)
        int r = tid >> 7;
        const T* pw = (const T*)p.pw;
        const float* glr = gl + r * 128;
        float acc = 0.f;
#pragma unroll 8
        for (int k = 0; k < 128; ++k) acc += glr[k] * cvt(pw[k * Dn + h]);
        yl[r * 128 + h] = acc + cvt(((const T*)p.pb)[h]);
    }
    __syncthreads();
    if (tid < 512) {   // mh = Yt@mw + mb : full dot per (r,h)
        int r = tid >> 7;
        const T* mw = (const T*)p.mw;
        const float* ylr = yl + r * 128;
        float acc = 0.f;
#pragma unroll 8
        for (int k = 0; k < 128; ++k) acc += ylr[k] * cvt(mw[k * Dn + h]);
        mh[(r0 + r) * Dn + h] = acc + cvt(((const T*)p.mb)[h]);
    }
}

// ---------------------------------------------------------------------------
// Phase 4+5 fused: per-column mh stats -> t build -> x stats.
// 256 blocks x 512 thr (1 token/thread; R2-verified body).
template <typename T>
__device__ void phase45(const KP& p, float* st, float* smem) {
    float* scr = smem;           // 16 floats
    int tid = threadIdx.x;
    int c = blockIdx.x;          // 0..255
    int b = c >> 7, d = c & 127;
    const float* mh = p.ws + WS_MH;
    const float* mp = mh + (size_t)b * Nn * Dn + d;
    float m0 = mp[(size_t)tid * Dn];
    float s = m0, ss = m0 * m0;
    blk512_sum2(s, ss, scr);
    float mm = s * (1.f / Nn);
    float vv = fmaxf(ss * (1.f / Nn) - mm * mm, 0.f);
    float rstd = rsqrtf(vv + 1e-5f);
    float scM = rstd * cvt(((const T*)p.n3w)[d]);
    float shM = cvt(((const T*)p.n3b)[d]) - mm * scM;
    const T* row = (const T*)p.row;
    float scI = st[ST_IN_SC + c], shI = st[ST_IN_SH + c];
    const T* rp = row + (size_t)b * Nn * Dn + d;
    float* tp = p.ws + WS_T + (size_t)b * Nn * Dn + d;
    float x0 = cvt(rp[(size_t)tid * Dn]) * scI + shI + m0 * scM + shM;
    tp[(size_t)tid * Dn] = x0;
    __syncthreads();
    float s2 = x0, ss2 = x0 * x0;
    blk512_sum2(s2, ss2, scr);
    if (tid == 0) {
        float m = s2 * (1.f / Nn);
        float v = fmaxf(ss2 * (1.f / Nn) - m * m, 0.f);
        float r = rsqrtf(v + 1e-5f);
        float sc = r * cvt(((const T*)p.f1w)[d]);
        st[ST_X_SC + c] = sc;
        st[ST_X_SH + c] = cvt(((const T*)p.f1b)[d]) - m * sc;
    }
}

// ---------------------------------------------------------------------------
// Phase 6: FFN (x normalized inline). 4 rows/block, 512 threads, 256 blocks.
template <typename T>
__device__ void phase6(const KP& p, float* st, float* smem) {
    int tid = threadIdx.x;
    int r0 = blockIdx.x * 4;
    int b = r0 >> 9;
    const float* t = p.ws + WS_T;
    float* outpre = p.ws + WS_OP;
    const T* w1 = (const T*)p.ffw1; const T* b1 = (const T*)p.ffb1;
    const T* w2 = (const T*)p.ffw2; const T* b2 = (const T*)p.ffb2;

    float* xl = smem;            // [4][128] = 512
    float* hl = smem + 512;      // [4][512] = 2048
    float* red = smem + 2560;    // [4(q)][4(r)][128] = 2048
    {
        int r = tid >> 7, d = tid & 127;
        int c = b * 128 + d;
        xl[r * 128 + d] = t[(r0 + r) * Dn + d] * st[ST_X_SC + c] + st[ST_X_SH + c];
    }
    __syncthreads();
    {
        int f = tid;
        float a[4] = {0,0,0,0};
#pragma unroll 4
        for (int k = 0; k < Dn; ++k) {
            float w = cvt(w1[k * FHn + f]);
#pragma unroll
            for (int r = 0; r < 4; ++r) a[r] += xl[r * 128 + k] * w;
        }
        float bb1 = cvt(b1[f]);
#pragma unroll
        for (int r = 0; r < 4; ++r) hl[r * 512 + f] = fmaxf(a[r] + bb1, 0.f);
    }
    __syncthreads();
    {
        int d = tid & 127, q = tid >> 7;
        int k0 = q * 128;
        float a[4] = {0,0,0,0};
#pragma unroll 8
        for (int k = k0; k < k0 + 128; ++k) {
            float w = cvt(w2[k * Dn + d]);
#pragma unroll
            for (int r = 0; r < 4; ++r) a[r] += hl[r * 512 + k] * w;
        }
#pragma unroll
        for (int r = 0; r < 4; ++r) red[q * 512 + r * 128 + d] = a[r];
    }
    __syncthreads();
    if (tid < 128) {
        float bb2 = cvt(b2[tid]);
#pragma unroll
        for (int r = 0; r < 4; ++r) {
            float sum = red[r * 128 + tid] + red[512 + r * 128 + tid]
                      + red[1024 + r * 128 + tid] + red[1536 + r * 128 + tid];
            outpre[(r0 + r) * Dn + tid] = xl[r * 128 + tid] + sum + bb2;
        }
    }
}

// ---------------------------------------------------------------------------
// Phase 7+8 fused: per-column outpre stats -> cast out.
// 256 blocks x 512 thr (1 token/thread; R2-verified body).
template <typename T>
__device__ void phase78(const KP& p, float* smem) {
    float* scr = smem;           // 16 floats
    int tid = threadIdx.x;
    int c = blockIdx.x;          // 0..255
    int b = c >> 7, d = c & 127;
    const float* op = p.ws + WS_OP;
    const float* sp = op + (size_t)b * Nn * Dn + d;
    float x0 = sp[(size_t)tid * Dn];
    float s = x0, ss = x0 * x0;
    blk512_sum2(s, ss, scr);
    float m = s * (1.f / Nn);
    float v = fmaxf(ss * (1.f / Nn) - m * m, 0.f);
    float rstd = rsqrtf(v + 1e-5f);
    float sc = rstd * cvt(((const T*)p.f2w)[d]);
    float sh = cvt(((const T*)p.f2b)[d]) - m * sc;
    T* out = (T*)p.out + (size_t)b * Nn * Dn + d;
    out[(size_t)tid * Dn] = (T)(x0 * sc + sh);
}

// ---------------------------------------------------------------------------
// Kernel wrappers
__global__ __launch_bounds__(256) void k_head(KP p) {
    __shared__ float smem[SMEM_FLOATS];
    float* st = p.ws + WS_ST;
    if (is_bf16(p.alpha)) phase0<bf16>(p, st, smem);
    else                  phase0<float>(p, st, smem);
}
__global__ __launch_bounds__(512) void k_qkv(KP p) {
    __shared__ float smem[7168];
    float* st = p.ws + WS_ST;
    if (is_bf16(p.alpha)) phase1<bf16>(p, st, smem);
    else                  phase1<float>(p, st, smem);
}
__global__ __launch_bounds__(512) void k_kekv(KP p) {
    __shared__ float smem[16];
    phase2(p, smem);
}
__global__ __launch_bounds__(1024) void k_attn(KP p) {
    __shared__ float smem[11328];   // 45.3 KB
    float* st = p.ws + WS_ST;
    if (is_bf16(p.alpha)) phase3<bf16>(p, st, smem);
    else                  phase3<float>(p, st, smem);
}
__global__ __launch_bounds__(512) void k_mid(KP p) {
    __shared__ float smem[16];
    float* st = p.ws + WS_ST;
    if (is_bf16(p.alpha)) phase45<bf16>(p, st, smem);
    else                  phase45<float>(p, st, smem);
}
__global__ __launch_bounds__(512) void k_ffn(KP p) {
    __shared__ float smem[4608];   // 18 KB
    float* st = p.ws + WS_ST;
    if (is_bf16(p.alpha)) phase6<bf16>(p, st, smem);
    else                  phase6<float>(p, st, smem);
}
__global__ __launch_bounds__(512) void k_tail(KP p) {
    __shared__ float smem[16];
    if (is_bf16(p.alpha)) phase78<bf16>(p, smem);
    else                  phase78<float>(p, smem);
}

// ---------------------------------------------------------------------------
extern "C" void kernel_launch(void* const* d_in, const int* in_sizes, int n_in,
                              void* d_out, int out_size, void* d_ws, size_t ws_size,
                              hipStream_t stream) {
    KP p;
    p.row = d_in[0];  p.col = d_in[1];  p.cost = d_in[2];  p.coords = d_in[3];
    p.alpha = d_in[4];
    p.n1w = d_in[5];  p.n1b = d_in[6];  p.n2w = d_in[7];  p.n2b = d_in[8];
    p.n3w = d_in[9];  p.n3b = d_in[10]; p.f1w = d_in[11]; p.f1b = d_in[12];
    p.f2w = d_in[13]; p.f2b = d_in[14];
    p.qw = d_in[15];  p.qb = d_in[16];  p.kw = d_in[17];  p.kb = d_in[18];
    p.vw = d_in[19];  p.vb = d_in[20];  p.pw = d_in[21];  p.pb = d_in[22];
    p.mw = d_in[23];  p.mb = d_in[24];
    p.dw1 = d_in[25]; p.db1 = d_in[26]; p.dw2 = d_in[27]; p.db2 = d_in[28];
    p.aw1 = d_in[29]; p.ab1 = d_in[30]; p.aw2 = d_in[31]; p.ab2 = d_in[32];
    p.gw = d_in[33];  p.gb = d_in[34];  p.ow = d_in[35];  p.ob = d_in[36];
    p.ffw1 = d_in[37]; p.ffb1 = d_in[38]; p.ffw2 = d_in[39]; p.ffb2 = d_in[40];
    p.out = d_out;
    p.ws = (float*)d_ws;

    k_head<<<512, 256, 0, stream>>>(p);
    k_qkv<<<256, 512, 0, stream>>>(p);
    k_kekv<<<256, 512, 0, stream>>>(p);
    k_attn<<<256, 1024, 0, stream>>>(p);
    k_mid<<<256, 512, 0, stream>>>(p);
    k_ffn<<<256, 512, 0, stream>>>(p);
    k_tail<<<256, 512, 0, stream>>>(p);
}

// Round 7
// 229.312 us; speedup vs baseline: 1.1047x; 1.0054x over previous
//
#include <hip/hip_runtime.h>
#include <hip/hip_bf16.h>
#include <hip/hip_fp16.h>
#include <math.h>

// Problem constants
#define Bn  2
#define Nn  512
#define Dn  128
#define FHn 512

#define PI_F 3.14159265358979323846f

typedef __hip_bfloat16 bf16;

__device__ __forceinline__ float cvt(float x) { return x; }
__device__ __forceinline__ float cvt(bf16 x) { return __bfloat162float(x); }
__device__ __forceinline__ float sigmoidf_(float x) { return 1.0f / (1.0f + __expf(-x)); }
__device__ __forceinline__ bool is_bf16(const void* alpha) {
    return ((const unsigned short*)alpha)[0] == 0x3F80;
}

// fast atan2, max abs err ~2e-5 rad (output guaranteed in [-pi, pi])
__device__ __forceinline__ float fatan2f(float dy, float dx) {
    float ax = fabsf(dx), ay = fabsf(dy);
    float mx = fmaxf(ax, ay), mn = fminf(ax, ay);
    float r = __fdividef(mn, mx);
    float t = r * r;
    float a = r * (0.99997726f + t * (-0.33262347f + t * (0.19354346f +
              t * (-0.11643287f + t * (0.05265332f + t * (-0.01172120f))))));
    if (ay > ax) a = 1.57079632679489662f - a;
    if (dx < 0.f) a = PI_F - a;
    if (dy < 0.f) a = -a;
    return fminf(fmaxf(a, -PI_F), PI_F);
}

// ---------------------------------------------------------------------------
// Workspace layout (float offsets). S = one (B,N,D) f32 slab.
// eK/eKV packed as __half2 {eK, eKV} per (j,h) in the WS_EK slab (R7).
#define S_ 131072
#define WS_Q    (0 * S_)
#define WS_K    (1 * S_)
#define WS_V    (2 * S_)
#define WS_EK   (3 * S_)
#define WS_EKV  (4 * S_)   // unused since R7 (packed into WS_EK)
#define WS_MH   (5 * S_)
#define WS_T    (6 * S_)
#define WS_OP   (7 * S_)
#define WS_ST   (8 * S_)

// stats region (float offsets inside WS_ST)
#define ST_IN_SC   0      // 512: [which*256 + b*128 + d]
#define ST_IN_SH   512
#define ST_X_SC    2048
#define ST_X_SH    2304
#define ST_PRE     3072
#define P_SC       1024   // cds, cdt, cas, cat, gate_b, outlin_b, alpha (7)
#define ST_TAB     4224   // 1288 floats of piecewise-linear tables
#define TAB_ANG 644
#define TAB_N   1288
// bucket->segment LUTs (257 each), contiguous right after the tables
#define ST_LUTC (ST_TAB + TAB_N)        // 5512
#define ST_LUTA (ST_LUTC + 257)         // 5769
#define TABLUT_N (TAB_N + 514)          // 1802 contiguous floats

#define SMEM_FLOATS 2568   // 2560 work + 8 reduce scratch (256-thread kernels)

struct KP {
    const void *row, *col, *cost, *coords, *alpha;
    const void *n1w, *n1b, *n2w, *n2b, *n3w, *n3b, *f1w, *f1b, *f2w, *f2b;
    const void *qw, *qb, *kw, *kb, *vw, *vb, *pw, *pb, *mw, *mb;
    const void *dw1, *db1, *dw2, *db2, *aw1, *ab1, *aw2, *ab2, *gw, *gb, *ow, *ob;
    const void *ffw1, *ffb1, *ffw2, *ffb2;
    void* out;
    float* ws;
};

// ---------------------------------------------------------------------------
// Block-level reductions (256 threads). scr >= 8 floats. All threads get result.
__device__ __forceinline__ void blk_sum2(float& s, float& ss, volatile float* scr) {
#pragma unroll
    for (int off = 32; off > 0; off >>= 1) { s += __shfl_down(s, off); ss += __shfl_down(ss, off); }
    __syncthreads();
    int wave = threadIdx.x >> 6, lane = threadIdx.x & 63;
    if (lane == 0) { scr[wave] = s; scr[4 + wave] = ss; }
    __syncthreads();
    s = scr[0] + scr[1] + scr[2] + scr[3];
    ss = scr[4] + scr[5] + scr[6] + scr[7];
}

// 512-thread block reductions. scr >= 16 floats.
__device__ __forceinline__ void blk512_sum2(float& s, float& ss, volatile float* scr) {
#pragma unroll
    for (int off = 32; off > 0; off >>= 1) { s += __shfl_down(s, off); ss += __shfl_down(ss, off); }
    __syncthreads();
    int wave = threadIdx.x >> 6, lane = threadIdx.x & 63;
    if (lane == 0) { scr[wave] = s; scr[8 + wave] = ss; }
    __syncthreads();
    s = 0.f; ss = 0.f;
#pragma unroll
    for (int w = 0; w < 8; ++w) { s += scr[w]; ss += scr[8 + w]; }
}

__device__ __forceinline__ float blk512_sum1(float v, volatile float* scr) {
#pragma unroll
    for (int off = 32; off > 0; off >>= 1) v += __shfl_down(v, off);
    __syncthreads();
    int wave = threadIdx.x >> 6, lane = threadIdx.x & 63;
    if (lane == 0) scr[wave] = v;
    __syncthreads();
    float s = 0.f;
#pragma unroll
    for (int w = 0; w < 8; ++w) s += scr[w];
    return s;
}

__device__ __forceinline__ float blk512_max1(float v, volatile float* scr) {
#pragma unroll
    for (int off = 32; off > 0; off >>= 1) v = fmaxf(v, __shfl_down(v, off));
    __syncthreads();
    int wave = threadIdx.x >> 6, lane = threadIdx.x & 63;
    if (lane == 0) scr[wave] = v;
    __syncthreads();
    float m = scr[0];
#pragma unroll
    for (int w = 1; w < 8; ++w) m = fmaxf(m, scr[w]);
    return m;
}

// ---------------------------------------------------------------------------
// Build piecewise-linear tables for one scalar MLP — fully parallel.
// Also leaves the SORTED breakpoints in smem+768 (128 floats) for LUT build.
template <typename T>
__device__ void build_tables(const T* w1p, const T* b1p, const T* w2p,
                             const T* owp, const T* gwp, float* gtab, float* smem) {
    int tid = threadIdx.x;
    float* W  = smem;          // 128
    float* Bb = smem + 128;
    float* U  = smem + 256;
    float* Vv = smem + 384;
    float* Tt = smem + 512;
    int* RK   = (int*)(smem + 640);   // 128 ranks
    float* STl = smem + 768;          // sorted breakpoints (LDS copy)
    if (tid < 128) {
        float u = 0.f, v = 0.f;
#pragma unroll 4
        for (int d = 0; d < Dn; ++d) {
            float w2 = cvt(w2p[tid * Dn + d]);
            u += w2 * cvt(owp[d]);
            v += w2 * cvt(gwp[d]);
        }
        float w = cvt(w1p[tid]), b = cvt(b1p[tid]);
        U[tid] = u; Vv[tid] = v; W[tid] = w; Bb[tid] = b;
        Tt[tid] = (w != 0.f) ? (-b / w) : 3.0e38f;
    }
    __syncthreads();
    if (tid < 128) {
        float tk = Tt[tid]; int r = 0;
        for (int j = 0; j < 128; ++j) {
            float tj = Tt[j];
            r += (tj < tk) || (tj == tk && j < tid);
        }
        RK[tid] = r;
        gtab[r] = tk;        // sorted breakpoint table (scatter by rank)
        STl[r] = tk;         // LDS copy for LUT build
    }
    __syncthreads();
    if (tid <= 128) {
        int si = tid;
        float slS = 0, inS = 0, slT = 0, inT = 0;
        for (int k = 0; k < 128; ++k) {
            float w = W[k];
            if (w == 0.f) {
                float rb = fmaxf(Bb[k], 0.f);
                inS += rb * U[k];
                inT += rb * Vv[k];
            } else {
                bool act = (w > 0.f) ? (RK[k] < si) : (RK[k] >= si);
                if (act) {
                    slS += w * U[k];  inS += Bb[k] * U[k];
                    slT += w * Vv[k]; inT += Bb[k] * Vv[k];
                }
            }
        }
        gtab[128 + si] = slS;
        gtab[257 + si] = inS;
        gtab[386 + si] = slT;
        gtab[515 + si] = inT;
    }
}

// count of sorted breakpoints <= c over LDS array of 128
__device__ __forceinline__ int bsearch128(const float* T, float c) {
    int lo = 0, hi = 128;
    while (lo < hi) { int mid = (lo + hi) >> 1; if (T[mid] <= c) lo = mid + 1; else hi = mid; }
    return lo;
}

// ---------------------------------------------------------------------------
// Phase 0: input instance-norm stats (512 cols, 1/block); block 128 = scalar
// constants; blocks 129/130 = dist/angle piecewise tables + bucket LUTs.
template <typename T>
__device__ void phase0(const KP& p, float* st, float* smem) {
    float* scr = smem + 2560;
    int cid = blockIdx.x;    // 0..511
    int tid = threadIdx.x;
    {
        int which = cid >> 8, b = (cid >> 7) & 1, d = cid & 127;
        const T* src = (const T*)(which ? p.col : p.row) + (size_t)b * Nn * Dn + d;
        float x0 = cvt(src[(size_t)tid * Dn]);
        float x1 = cvt(src[(size_t)(tid + 256) * Dn]);
        float s = x0 + x1, ss = x0 * x0 + x1 * x1;
        blk_sum2(s, ss, scr);
        if (tid == 0) {
            float m = s * (1.f / Nn);
            float v = fmaxf(ss * (1.f / Nn) - m * m, 0.f);
            float rstd = rsqrtf(v + 1e-5f);
            const T* w = which ? (const T*)p.n2w : (const T*)p.n1w;
            const T* bb = which ? (const T*)p.n2b : (const T*)p.n1b;
            float sc = rstd * cvt(w[d]);
            st[ST_IN_SC + cid] = sc;
            st[ST_IN_SH + cid] = cvt(bb[d]) - m * sc;
        }
    }
    __syncthreads();
    if (cid == 128) {
        const T* db2 = (const T*)p.db2; const T* ab2 = (const T*)p.ab2;
        const T* ow = (const T*)p.ow;   const T* gw = (const T*)p.gw;
        float d2 = 0.f, a2 = 0.f, o = 0.f, g0 = 0.f, g1 = 0.f;
        if (tid < 128) {
            d2 = cvt(db2[tid]); a2 = cvt(ab2[tid]);
            o = cvt(ow[tid]); g0 = cvt(gw[tid]); g1 = cvt(gw[Dn + tid]);
        }
        float cds = d2 * o, cdt = d2 * g0, cas = a2 * o, cat = a2 * g1;
        blk_sum2(cds, cdt, scr);
        blk_sum2(cas, cat, scr);
        if (tid == 0) {
            float* pre = st + ST_PRE;
            pre[P_SC + 0] = cds; pre[P_SC + 1] = cdt;
            pre[P_SC + 2] = cas; pre[P_SC + 3] = cat;
            pre[P_SC + 4] = cvt(((const T*)p.gb)[0]);
            pre[P_SC + 5] = cvt(((const T*)p.ob)[0]);
            pre[P_SC + 6] = cvt(((const T*)p.alpha)[0]);
        }
    } else if (cid == 129) {
        build_tables<T>((const T*)p.dw1, (const T*)p.db1, (const T*)p.dw2,
                        (const T*)p.ow, (const T*)p.gw, st + ST_TAB, smem);
        __syncthreads();
        const float* STl = smem + 768;
        for (int e = tid; e < 257; e += 256) {
            float c = e * (1.f / 256.f);                 // cost domain [0,1]
            st[ST_LUTC + e] = (float)bsearch128(STl, c);
        }
    } else if (cid == 130) {
        build_tables<T>((const T*)p.aw1, (const T*)p.ab1, (const T*)p.aw2,
                        (const T*)p.ow, (const T*)p.gw + Dn, st + ST_TAB + TAB_ANG, smem);
        __syncthreads();
        const float* STl = smem + 768;
        for (int e = tid; e < 257; e += 256) {
            float a = -PI_F + e * (PI_F / 128.f);        // angle domain [-pi,pi]
            st[ST_LUTA + e] = (float)bsearch128(STl, a);
        }
    }
}

// ---------------------------------------------------------------------------
// Phase 1: QKV only. 4 rows/block, 512 threads, 256 blocks.
template <typename T>
__device__ void phase1(const KP& p, float* st, float* smem) {
    int tid = threadIdx.x;
    int r0 = blockIdx.x * 4;     // rows r0..r0+3 (0..1023)
    int b = r0 >> 9;
    const T* row = (const T*)p.row; const T* col = (const T*)p.col;
    float* ws = p.ws;
    float* Q = ws + WS_Q; float* Kraw = ws + WS_K; float* V = ws + WS_V;

    float* lr = smem;            // [4][128]
    float* lc = smem + 512;      // [4][128]
    float* redq = smem + 1024;   // [4(q)][4(r)][128]
    float* redk = smem + 3072;
    float* redv = smem + 5120;
    {
        int r = tid >> 7, d = tid & 127;
        float scR = st[ST_IN_SC + b * 128 + d],       shR = st[ST_IN_SH + b * 128 + d];
        float scC = st[ST_IN_SC + 256 + b * 128 + d], shC = st[ST_IN_SH + 256 + b * 128 + d];
        lr[r * 128 + d] = cvt(row[(size_t)(r0 + r) * Dn + d]) * scR + shR;
        lc[r * 128 + d] = cvt(col[(size_t)(r0 + r) * Dn + d]) * scC + shC;
    }
    __syncthreads();
    {
        int h = tid & 127, q = tid >> 7;
        const T* qw = (const T*)p.qw; const T* kw = (const T*)p.kw; const T* vw = (const T*)p.vw;
        float aq[4] = {0,0,0,0}, ak[4] = {0,0,0,0}, av[4] = {0,0,0,0};
        int ks = q * 32;
#pragma unroll 8
        for (int k = ks; k < ks + 32; ++k) {
            float wq = cvt(qw[k * Dn + h]);
            float wk = cvt(kw[k * Dn + h]);
            float wv = cvt(vw[k * Dn + h]);
#pragma unroll
            for (int r = 0; r < 4; ++r) {
                aq[r] += lr[r * 128 + k] * wq;
                ak[r] += lc[r * 128 + k] * wk;
                av[r] += lc[r * 128 + k] * wv;
            }
        }
#pragma unroll
        for (int r = 0; r < 4; ++r) {
            redq[q * 512 + r * 128 + h] = aq[r];
            redk[q * 512 + r * 128 + h] = ak[r];
            redv[q * 512 + r * 128 + h] = av[r];
        }
    }
    __syncthreads();
    if (tid < 128) {
        int h = tid;
        float bq = cvt(((const T*)p.qb)[h]);
        float bk = cvt(((const T*)p.kb)[h]);
        float bv = cvt(((const T*)p.vb)[h]);
#pragma unroll
        for (int r = 0; r < 4; ++r) {
            float qv = redq[r*128+h] + redq[512 + r*128+h] + redq[1024 + r*128+h] + redq[1536 + r*128+h] + bq;
            float kv = redk[r*128+h] + redk[512 + r*128+h] + redk[1024 + r*128+h] + redk[1536 + r*128+h] + bk;
            float vv = redv[r*128+h] + redv[512 + r*128+h] + redv[1024 + r*128+h] + redv[1536 + r*128+h] + bv;
            Q[(r0 + r) * Dn + h]    = sigmoidf_(qv);
            Kraw[(r0 + r) * Dn + h] = kv;
            V[(r0 + r) * Dn + h]    = vv;
        }
    }
}

// ---------------------------------------------------------------------------
// Phase 2: K-softmax over tokens; writes PACKED __half2{eK, eKV} per (j,h).
// 256 blocks x 512 thr (1 token/thread).
__device__ void phase2(const KP& p, float* smem) {
    float* scr = smem;           // 16 floats
    int tid = threadIdx.x;
    int c = blockIdx.x;          // 0..255
    int b = c >> 7, h = c & 127;
    float* ws = p.ws;
    const float* Kraw = ws + WS_K;
    const float* V = ws + WS_V;
    __half2* ekv2 = (__half2*)(ws + WS_EK);
    const float* kb = Kraw + (size_t)b * Nn * Dn + h;
    const float* vb = V + (size_t)b * Nn * Dn + h;
    float x0 = kb[(size_t)tid * Dn];
    float mx = blk512_max1(x0, scr);
    float e0 = __expf(x0 - mx);
    float s = blk512_sum1(e0, scr);
    float rs = 1.f / s;
    float ek0 = __expf(e0 * rs);
    float ev0 = ek0 * vb[(size_t)tid * Dn];
    __half2 hv;
    hv.x = __float2half(ek0);
    hv.y = __float2half(ev0);
    ekv2[(size_t)b * Nn * Dn + (size_t)tid * Dn + h] = hv;
}

// ---------------------------------------------------------------------------
// Phase 3 (fused): eab inline + num/den from packed f16 eK/eKV + p/mhc
// projections. 256 blocks x 1024 thr.
// LDS: ab[2048] | redn[4096] | redd[4096] | gl[512] | yl[512] | scr[64] = 11328
//      tab+luts [1802] overlaid on redn during eab step.
template <typename T>
__device__ void phase3(const KP& p, float* st, float* smem) {
    int tid = threadIdx.x;
    int r0 = blockIdx.x * 4;
    int b = r0 >> 9;
    float* ws = p.ws;
    const __half2* ekv2 = (const __half2*)(ws + WS_EK);
    const float* Q = ws + WS_Q;
    float* mh = ws + WS_MH;

    float* ab   = smem;          // 2048
    float* redn = smem + 2048;   // 4096
    float* redd = smem + 6144;   // 4096
    float* gl   = smem + 10240;  // 512
    float* yl   = smem + 10752;  // 512
    float* scr  = smem + 11264;  // 64

    // ---- step 1: eab for rows r0..r0+3; thread = (j = tid&511, row-pair) ----
    {
        float* tab  = smem + 2048;   // [1288] overlays redn
        float* lutc = smem + 3336;   // [257]
        float* luta = smem + 3593;   // [257]  (ends 3850 < 6144)
        const float* gt = st + ST_TAB;
        for (int e = tid; e < TABLUT_N; e += 1024) tab[e] = gt[e];
        __syncthreads();
        const float* pre = st + ST_PRE;
        float cds = pre[P_SC + 0], cdt = pre[P_SC + 1], cas = pre[P_SC + 2], cat = pre[P_SC + 3];
        float gbias = pre[P_SC + 4], obias = pre[P_SC + 5], alpha = pre[P_SC + 6];
        const T* cost = (const T*)p.cost;
        const T* coords = (const T*)p.coords;
        const float* tabA = tab + TAB_ANG;

        int j = tid & 511;
        int rp = tid >> 9;           // 0 or 1 -> rows 2rp, 2rp+1
        float cjx = cvt(coords[((size_t)b * Nn + j) * 2 + 0]);
        float cjy = cvt(coords[((size_t)b * Nn + j) * 2 + 1]);
        float av[2];
#pragma unroll
        for (int rr = 0; rr < 2; ++rr) {
            int row = rp * 2 + rr;
            int i = (r0 + row) & 511;
            float cix = cvt(coords[((size_t)b * Nn + i) * 2 + 0]);
            float ciy = cvt(coords[((size_t)b * Nn + i) * 2 + 1]);
            float c = cvt(cost[(size_t)b * Nn * Nn + (size_t)i * Nn + j]);
            int k = (int)(c * 256.f); k = k < 0 ? 0 : (k > 255 ? 255 : k);
            int lo = (int)lutc[k], hi = (int)lutc[k + 1];
            while (lo < hi && tab[lo] <= c) ++lo;
            float sd = fmaf(tab[128 + lo], c, tab[257 + lo]) + cds;
            float td = fmaf(tab[386 + lo], c, tab[515 + lo]) + cdt;
            float dx = cix - cjx;
            float dy = ciy - cjy;
            float ang = (dx == 0.f && dy == 0.f) ? 0.f : fatan2f(dy, dx);
            int ka = (int)((ang + PI_F) * (128.f / PI_F)); ka = ka < 0 ? 0 : (ka > 255 ? 255 : ka);
            int la = (int)luta[ka], ha = (int)luta[ka + 1];
            while (la < ha && tabA[la] <= ang) ++la;
            float sa = fmaf(tabA[128 + la], ang, tabA[257 + la]) + cas;
            float ta = fmaf(tabA[386 + la], ang, tabA[515 + la]) + cat;
            float gv = sigmoidf_(td + ta + gbias);
            av[rr] = alpha * (gv * sd + (1.f - gv) * sa + obias);
        }
        // per-row softmax over 512: row (2rp+rr)'s values live in waves rp*8..rp*8+7
        int wave = tid >> 6, lane = tid & 63, w8 = wave & 7;
        float t0 = av[0], t1 = av[1];
#pragma unroll
        for (int off = 32; off > 0; off >>= 1) {
            t0 = fmaxf(t0, __shfl_down(t0, off));
            t1 = fmaxf(t1, __shfl_down(t1, off));
        }
        __syncthreads();   // fences tab reads before scr use
        if (lane == 0) { scr[(rp * 2) * 8 + w8] = t0; scr[(rp * 2 + 1) * 8 + w8] = t1; }
        __syncthreads();
        float ev[2];
#pragma unroll
        for (int rr = 0; rr < 2; ++rr) {
            int row = rp * 2 + rr;
            float m = scr[row * 8];
#pragma unroll
            for (int w = 1; w < 8; ++w) m = fmaxf(m, scr[row * 8 + w]);
            ev[rr] = __expf(av[rr] - m);
        }
        float s0 = ev[0], s1 = ev[1];
#pragma unroll
        for (int off = 32; off > 0; off >>= 1) {
            s0 += __shfl_down(s0, off);
            s1 += __shfl_down(s1, off);
        }
        if (lane == 0) { scr[32 + (rp * 2) * 8 + w8] = s0; scr[32 + (rp * 2 + 1) * 8 + w8] = s1; }
        __syncthreads();
#pragma unroll
        for (int rr = 0; rr < 2; ++rr) {
            int row = rp * 2 + rr;
            float s = 0.f;
#pragma unroll
            for (int w = 0; w < 8; ++w) s += scr[32 + row * 8 + w];
            ab[row * 512 + j] = __expf(ev[rr] / s);
        }
    }
    __syncthreads();   // ab complete; tab region free for redn reuse

    int h = tid & 127, q = tid >> 7;   // q in 0..7 (64-j eighths)
    int j0 = q * 64;

    // ---- step 2: num/den from packed f16 eK/eKV (one 4B load per (j,h)) ----
    {
        const __half2* eb = ekv2 + (size_t)b * Nn * Dn + h;
        float num[4] = {0,0,0,0}, den[4] = {0,0,0,0};
#pragma unroll 4
        for (int j = j0; j < j0 + 64; ++j) {
            __half2 kv = eb[(size_t)j * Dn];
            float ek = __half2float(kv.x);
            float ev_ = __half2float(kv.y);
#pragma unroll
            for (int r = 0; r < 4; ++r) {
                num[r] += ab[r * 512 + j] * ev_;
                den[r] += ab[r * 512 + j] * ek;
            }
        }
#pragma unroll
        for (int r = 0; r < 4; ++r) {
            redn[q * 512 + r * 128 + h] = num[r];
            redd[q * 512 + r * 128 + h] = den[r];
        }
    }
    __syncthreads();
    if (tid < 512) {
        int r = tid >> 7;   // (r, h) pair
        float nu = 0.f, de = 0.f;
#pragma unroll
        for (int qq = 0; qq < 8; ++qq) {
            nu += redn[qq * 512 + r * 128 + h];
            de += redd[qq * 512 + r * 128 + h];
        }
        gl[r * 128 + h] = Q[(r0 + r) * Dn + h] * nu / de;
    }
    __syncthreads();
    if (tid < 512) {   // Yt = G@pw + pb : full dot per (r,h)
        int r = tid >> 7;
        const T* pw = (const T*)p.pw;
        const float* glr = gl + r * 128;
        float acc = 0.f;
#pragma unroll 8
        for (int k = 0; k < 128; ++k) acc += glr[k] * cvt(pw[k * Dn + h]);
        yl[r * 128 + h] = acc + cvt(((const T*)p.pb)[h]);
    }
    __syncthreads();
    if (tid < 512) {   // mh = Yt@mw + mb : full dot per (r,h)
        int r = tid >> 7;
        const T* mw = (const T*)p.mw;
        const float* ylr = yl + r * 128;
        float acc = 0.f;
#pragma unroll 8
        for (int k = 0; k < 128; ++k) acc += ylr[k] * cvt(mw[k * Dn + h]);
        mh[(r0 + r) * Dn + h] = acc + cvt(((const T*)p.mb)[h]);
    }
}

// ---------------------------------------------------------------------------
// Phase 4+5 fused: per-column mh stats -> t build -> x stats.
// 256 blocks x 512 thr (1 token/thread).
template <typename T>
__device__ void phase45(const KP& p, float* st, float* smem) {
    float* scr = smem;           // 16 floats
    int tid = threadIdx.x;
    int c = blockIdx.x;          // 0..255
    int b = c >> 7, d = c & 127;
    const float* mh = p.ws + WS_MH;
    const float* mp = mh + (size_t)b * Nn * Dn + d;
    float m0 = mp[(size_t)tid * Dn];
    float s = m0, ss = m0 * m0;
    blk512_sum2(s, ss, scr);
    float mm = s * (1.f / Nn);
    float vv = fmaxf(ss * (1.f / Nn) - mm * mm, 0.f);
    float rstd = rsqrtf(vv + 1e-5f);
    float scM = rstd * cvt(((const T*)p.n3w)[d]);
    float shM = cvt(((const T*)p.n3b)[d]) - mm * scM;
    const T* row = (const T*)p.row;
    float scI = st[ST_IN_SC + c], shI = st[ST_IN_SH + c];
    const T* rp = row + (size_t)b * Nn * Dn + d;
    float* tp = p.ws + WS_T + (size_t)b * Nn * Dn + d;
    float x0 = cvt(rp[(size_t)tid * Dn]) * scI + shI + m0 * scM + shM;
    tp[(size_t)tid * Dn] = x0;
    __syncthreads();
    float s2 = x0, ss2 = x0 * x0;
    blk512_sum2(s2, ss2, scr);
    if (tid == 0) {
        float m = s2 * (1.f / Nn);
        float v = fmaxf(ss2 * (1.f / Nn) - m * m, 0.f);
        float r = rsqrtf(v + 1e-5f);
        float sc = r * cvt(((const T*)p.f1w)[d]);
        st[ST_X_SC + c] = sc;
        st[ST_X_SH + c] = cvt(((const T*)p.f1b)[d]) - m * sc;
    }
}

// ---------------------------------------------------------------------------
// Phase 6: FFN (x normalized inline). 4 rows/block, 512 threads, 256 blocks.
template <typename T>
__device__ void phase6(const KP& p, float* st, float* smem) {
    int tid = threadIdx.x;
    int r0 = blockIdx.x * 4;
    int b = r0 >> 9;
    const float* t = p.ws + WS_T;
    float* outpre = p.ws + WS_OP;
    const T* w1 = (const T*)p.ffw1; const T* b1 = (const T*)p.ffb1;
    const T* w2 = (const T*)p.ffw2; const T* b2 = (const T*)p.ffb2;

    float* xl = smem;            // [4][128] = 512
    float* hl = smem + 512;      // [4][512] = 2048
    float* red = smem + 2560;    // [4(q)][4(r)][128] = 2048
    {
        int r = tid >> 7, d = tid & 127;
        int c = b * 128 + d;
        xl[r * 128 + d] = t[(r0 + r) * Dn + d] * st[ST_X_SC + c] + st[ST_X_SH + c];
    }
    __syncthreads();
    {
        int f = tid;
        float a[4] = {0,0,0,0};
#pragma unroll 4
        for (int k = 0; k < Dn; ++k) {
            float w = cvt(w1[k * FHn + f]);
#pragma unroll
            for (int r = 0; r < 4; ++r) a[r] += xl[r * 128 + k] * w;
        }
        float bb1 = cvt(b1[f]);
#pragma unroll
        for (int r = 0; r < 4; ++r) hl[r * 512 + f] = fmaxf(a[r] + bb1, 0.f);
    }
    __syncthreads();
    {
        int d = tid & 127, q = tid >> 7;
        int k0 = q * 128;
        float a[4] = {0,0,0,0};
#pragma unroll 8
        for (int k = k0; k < k0 + 128; ++k) {
            float w = cvt(w2[k * Dn + d]);
#pragma unroll
            for (int r = 0; r < 4; ++r) a[r] += hl[r * 512 + k] * w;
        }
#pragma unroll
        for (int r = 0; r < 4; ++r) red[q * 512 + r * 128 + d] = a[r];
    }
    __syncthreads();
    if (tid < 128) {
        float bb2 = cvt(b2[tid]);
#pragma unroll
        for (int r = 0; r < 4; ++r) {
            float sum = red[r * 128 + tid] + red[512 + r * 128 + tid]
                      + red[1024 + r * 128 + tid] + red[1536 + r * 128 + tid];
            outpre[(r0 + r) * Dn + tid] = xl[r * 128 + tid] + sum + bb2;
        }
    }
}

// ---------------------------------------------------------------------------
// Phase 7+8 fused: per-column outpre stats -> cast out.
// 256 blocks x 512 thr (1 token/thread).
template <typename T>
__device__ void phase78(const KP& p, float* smem) {
    float* scr = smem;           // 16 floats
    int tid = threadIdx.x;
    int c = blockIdx.x;          // 0..255
    int b = c >> 7, d = c & 127;
    const float* op = p.ws + WS_OP;
    const float* sp = op + (size_t)b * Nn * Dn + d;
    float x0 = sp[(size_t)tid * Dn];
    float s = x0, ss = x0 * x0;
    blk512_sum2(s, ss, scr);
    float m = s * (1.f / Nn);
    float v = fmaxf(ss * (1.f / Nn) - m * m, 0.f);
    float rstd = rsqrtf(v + 1e-5f);
    float sc = rstd * cvt(((const T*)p.f2w)[d]);
    float sh = cvt(((const T*)p.f2b)[d]) - m * sc;
    T* out = (T*)p.out + (size_t)b * Nn * Dn + d;
    out[(size_t)tid * Dn] = (T)(x0 * sc + sh);
}

// ---------------------------------------------------------------------------
// Kernel wrappers
__global__ __launch_bounds__(256) void k_head(KP p) {
    __shared__ float smem[SMEM_FLOATS];
    float* st = p.ws + WS_ST;
    if (is_bf16(p.alpha)) phase0<bf16>(p, st, smem);
    else                  phase0<float>(p, st, smem);
}
__global__ __launch_bounds__(512) void k_qkv(KP p) {
    __shared__ float smem[7168];
    float* st = p.ws + WS_ST;
    if (is_bf16(p.alpha)) phase1<bf16>(p, st, smem);
    else                  phase1<float>(p, st, smem);
}
__global__ __launch_bounds__(512) void k_kekv(KP p) {
    __shared__ float smem[16];
    phase2(p, smem);
}
__global__ __launch_bounds__(1024) void k_attn(KP p) {
    __shared__ float smem[11328];   // 45.3 KB
    float* st = p.ws + WS_ST;
    if (is_bf16(p.alpha)) phase3<bf16>(p, st, smem);
    else                  phase3<float>(p, st, smem);
}
__global__ __launch_bounds__(512) void k_mid(KP p) {
    __shared__ float smem[16];
    float* st = p.ws + WS_ST;
    if (is_bf16(p.alpha)) phase45<bf16>(p, st, smem);
    else                  phase45<float>(p, st, smem);
}
__global__ __launch_bounds__(512) void k_ffn(KP p) {
    __shared__ float smem[4608];   // 18 KB
    float* st = p.ws + WS_ST;
    if (is_bf16(p.alpha)) phase6<bf16>(p, st, smem);
    else                  phase6<float>(p, st, smem);
}
__global__ __launch_bounds__(512) void k_tail(KP p) {
    __shared__ float smem[16];
    if (is_bf16(p.alpha)) phase78<bf16>(p, smem);
    else                  phase78<float>(p, smem);
}

// ---------------------------------------------------------------------------
extern "C" void kernel_launch(void* const* d_in, const int* in_sizes, int n_in,
                              void* d_out, int out_size, void* d_ws, size_t ws_size,
                              hipStream_t stream) {
    KP p;
    p.row = d_in[0];  p.col = d_in[1];  p.cost = d_in[2];  p.coords = d_in[3];
    p.alpha = d_in[4];
    p.n1w = d_in[5];  p.n1b = d_in[6];  p.n2w = d_in[7];  p.n2b = d_in[8];
    p.n3w = d_in[9];  p.n3b = d_in[10]; p.f1w = d_in[11]; p.f1b = d_in[12];
    p.f2w = d_in[13]; p.f2b = d_in[14];
    p.qw = d_in[15];  p.qb = d_in[16];  p.kw = d_in[17];  p.kb = d_in[18];
    p.vw = d_in[19];  p.vb = d_in[20];  p.pw = d_in[21];  p.pb = d_in[22];
    p.mw = d_in[23];  p.mb = d_in[24];
    p.dw1 = d_in[25]; p.db1 = d_in[26]; p.dw2 = d_in[27]; p.db2 = d_in[28];
    p.aw1 = d_in[29]; p.ab1 = d_in[30]; p.aw2 = d_in[31]; p.ab2 = d_in[32];
    p.gw = d_in[33];  p.gb = d_in[34];  p.ow = d_in[35];  p.ob = d_in[36];
    p.ffw1 = d_in[37]; p.ffb1 = d_in[38]; p.ffw2 = d_in[39]; p.ffb2 = d_in[40];
    p.out = d_out;
    p.ws = (float*)d_ws;

    k_head<<<512, 256, 0, stream>>>(p);
    k_qkv<<<256, 512, 0, stream>>>(p);
    k_kekv<<<256, 512, 0, stream>>>(p);
    k_attn<<<256, 1024, 0, stream>>>(p);
    k_mid<<<256, 512, 0, stream>>>(p);
    k_ffn<<<256, 512, 0, stream>>>(p);
    k_tail<<<256, 512, 0, stream>>>(p);
}